// Round 11
// baseline (213.828 us; speedup 1.0000x reference)
//
#include <hip/hip_runtime.h>
#include <math.h>

// Problem constants
#define NREL 499        // 2*MAX_LEN-1
#define NREL_PAD 504    // fp16 row stride (1008 B, 16-B aligned)
#define LDB 72          // bf16 LDS row stride (flash kernel)
#define LDT 72          // bf16 LDS row stride (gemm tiles)

typedef __attribute__((ext_vector_type(8))) short bf16x8;
typedef __attribute__((ext_vector_type(4))) float f32x4;

__device__ __forceinline__ float bf2f(ushort x) {
  union { unsigned u; float f; } v; v.u = ((unsigned)x) << 16; return v.f;
}
__device__ __forceinline__ ushort f2bf(float x) {
  union { float f; unsigned u; } v; v.f = x;
  return (ushort)((v.u + 0x8000u) >> 16);
}
__device__ __forceinline__ ushort f2h(float x) {
  union { _Float16 h; ushort u; } v; v.h = (_Float16)x; return v.u;
}
__device__ __forceinline__ float h2f(ushort u) {
  union { _Float16 h; ushort u; } v; v.u = u; return (float)v.h;
}
__device__ __forceinline__ bf16x8 pack8(float4 a, float4 b) {
  bf16x8 r;
  r[0] = (short)f2bf(a.x); r[1] = (short)f2bf(a.y);
  r[2] = (short)f2bf(a.z); r[3] = (short)f2bf(a.w);
  r[4] = (short)f2bf(b.x); r[5] = (short)f2bf(b.y);
  r[6] = (short)f2bf(b.z); r[7] = (short)f2bf(b.w);
  return r;
}

// ============================================================================
// prep_wt: Wt[z][n][k] (bf16) = W_z[k][n], z = {q,k,v,o}. Grid (8,8,4).
// Blocks (0,0,z): build maskbf[b][j] = mask ? 1.0bf : 0.0bf.
// Blocks (1,0,z): build rel8[512][64] bf16 = 8 * rel (rows >= 499 zeroed).
// ============================================================================
__global__ __launch_bounds__(256) void prep_wt(const float* __restrict__ W0,
                                               const float* __restrict__ W1,
                                               const float* __restrict__ W2,
                                               const float* __restrict__ W3,
                                               const int* __restrict__ mask,
                                               const float* __restrict__ rel,
                                               ushort* __restrict__ Wt,
                                               ushort* __restrict__ maskbf,
                                               ushort* __restrict__ rel8) {
  __shared__ float T[64][68];
  const int t = threadIdx.x;
  const int k0 = blockIdx.x * 64, n0 = blockIdx.y * 64, z = blockIdx.z;
  const float* W = (z == 0) ? W0 : (z == 1) ? W1 : (z == 2) ? W2 : W3;
#pragma unroll
  for (int s = 0; s < 4; ++s) {
    int idx = t + s * 256;
    int r = idx >> 4, c4 = (idx & 15) << 2;
    *(float4*)&T[r][c4] = *(const float4*)(W + (size_t)(k0 + r) * 512 + n0 + c4);
  }
  if (blockIdx.x == 0 && blockIdx.y == 0) {
    int base = z * 1024 + t * 4;
    int4 mv = *(const int4*)(mask + base);
    ushort4 mo;
    mo.x = mv.x ? 0x3F80 : 0; mo.y = mv.y ? 0x3F80 : 0;
    mo.z = mv.z ? 0x3F80 : 0; mo.w = mv.w ? 0x3F80 : 0;
    *(ushort4*)(maskbf + base) = mo;
  } else if (blockIdx.x == 1 && blockIdx.y == 0) {
    int base = z * 8192 + t * 32;
#pragma unroll
    for (int c = 0; c < 4; ++c) {
      int e0 = base + c * 8;
      ushort tmp[8];
#pragma unroll
      for (int k = 0; k < 8; ++k) {
        int e = e0 + k;
        float v = (e < NREL * 64) ? rel[e] * 8.f : 0.f;
        tmp[k] = f2bf(v);
      }
      *(ushort4*)(rel8 + e0) = make_ushort4(tmp[0], tmp[1], tmp[2], tmp[3]);
      *(ushort4*)(rel8 + e0 + 4) = make_ushort4(tmp[4], tmp[5], tmp[6], tmp[7]);
    }
  }
  __syncthreads();
#pragma unroll
  for (int s = 0; s < 4; ++s) {
    int idx = t + s * 256;
    int row = idx >> 4, c4 = (idx & 15) << 2;  // row = n_local, c4 = k_local
    ushort4 u = make_ushort4(f2bf(T[c4 + 0][row]), f2bf(T[c4 + 1][row]),
                             f2bf(T[c4 + 2][row]), f2bf(T[c4 + 3][row]));
    *(ushort4*)(Wt + (size_t)z * 262144 + (size_t)(n0 + row) * 512 + k0 + c4) = u;
  }
}

// ============================================================================
// gemm_tile_body (64x64): C = A @ Wt^T + bias. Proven R4 structure.
// AFP32=1: A fp32 cast to bf16 during staging.
// MODE 0: fp32 row-major out; MODE 1: bf16 Vt [bh][d][l] masked-zeroed.
// ============================================================================
template <int MODE, int AFP32>
__device__ __forceinline__ void gemm_tile_body(const void* __restrict__ Av,
                                               const ushort* __restrict__ Wt,
                                               const float* __restrict__ bias,
                                               const int* __restrict__ mvec,
                                               void* __restrict__ outv,
                                               int bx, int by, float oscale) {
  __shared__ ushort As[64 * LDT];
  __shared__ ushort Bs[64 * LDT];
  const int t = threadIdx.x;
  const int lane = t & 63, wave = t >> 6;
  const int m16 = lane & 15, quad = lane >> 4;
  const int koff = quad << 3;
  const int i0 = by * 64, n0 = bx * 64;
  const int row0 = t >> 3, off0 = (t & 7) << 3;
  const int row1 = (t + 256) >> 3, off1 = ((t + 256) & 7) << 3;
  const ushort* Ab16 = (const ushort*)Av + (size_t)i0 * 512;
  const float*  Ab32 = (const float*)Av + (size_t)i0 * 512;
  const ushort* Bb = Wt + (size_t)n0 * 512;

  uint4 ar0, ar1;
  float4 af00, af01, af10, af11;
  if (AFP32) {
    af00 = *(const float4*)(Ab32 + (size_t)row0 * 512 + off0);
    af01 = *(const float4*)(Ab32 + (size_t)row0 * 512 + off0 + 4);
    af10 = *(const float4*)(Ab32 + (size_t)row1 * 512 + off1);
    af11 = *(const float4*)(Ab32 + (size_t)row1 * 512 + off1 + 4);
  } else {
    ar0 = *(const uint4*)(Ab16 + (size_t)row0 * 512 + off0);
    ar1 = *(const uint4*)(Ab16 + (size_t)row1 * 512 + off1);
  }
  uint4 br0 = *(const uint4*)(Bb + (size_t)row0 * 512 + off0);
  uint4 br1 = *(const uint4*)(Bb + (size_t)row1 * 512 + off1);

  f32x4 acc[4] = {{0.f, 0.f, 0.f, 0.f}, {0.f, 0.f, 0.f, 0.f},
                  {0.f, 0.f, 0.f, 0.f}, {0.f, 0.f, 0.f, 0.f}};

  for (int ks = 0; ks < 8; ++ks) {
    __syncthreads();
    if (AFP32) {
      *(bf16x8*)&As[row0 * LDT + off0] = pack8(af00, af01);
      *(bf16x8*)&As[row1 * LDT + off1] = pack8(af10, af11);
    } else {
      *(uint4*)&As[row0 * LDT + off0] = ar0;
      *(uint4*)&As[row1 * LDT + off1] = ar1;
    }
    *(uint4*)&Bs[row0 * LDT + off0] = br0;
    *(uint4*)&Bs[row1 * LDT + off1] = br1;
    __syncthreads();

    const int kn = ((ks + 1) & 7) << 6;
    if (AFP32) {
      af00 = *(const float4*)(Ab32 + (size_t)row0 * 512 + kn + off0);
      af01 = *(const float4*)(Ab32 + (size_t)row0 * 512 + kn + off0 + 4);
      af10 = *(const float4*)(Ab32 + (size_t)row1 * 512 + kn + off1);
      af11 = *(const float4*)(Ab32 + (size_t)row1 * 512 + kn + off1 + 4);
    } else {
      ar0 = *(const uint4*)(Ab16 + (size_t)row0 * 512 + kn + off0);
      ar1 = *(const uint4*)(Ab16 + (size_t)row1 * 512 + kn + off1);
    }
    br0 = *(const uint4*)(Bb + (size_t)row0 * 512 + kn + off0);
    br1 = *(const uint4*)(Bb + (size_t)row1 * 512 + kn + off1);

    __builtin_amdgcn_s_setprio(1);
    if (MODE != 1) {
#pragma unroll
      for (int kh = 0; kh < 2; ++kh) {
        bf16x8 af = *(const bf16x8*)&As[((wave << 4) + m16) * LDT + (kh << 5) + koff];
#pragma unroll
        for (int nt = 0; nt < 4; ++nt) {
          bf16x8 wf = *(const bf16x8*)&Bs[((nt << 4) + m16) * LDT + (kh << 5) + koff];
          acc[nt] = __builtin_amdgcn_mfma_f32_16x16x32_bf16(af, wf, acc[nt], 0, 0, 0);
        }
      }
    } else {
#pragma unroll
      for (int kh = 0; kh < 2; ++kh) {
        bf16x8 wf = *(const bf16x8*)&Bs[((wave << 4) + m16) * LDT + (kh << 5) + koff];
#pragma unroll
        for (int it = 0; it < 4; ++it) {
          bf16x8 af = *(const bf16x8*)&As[((it << 4) + m16) * LDT + (kh << 5) + koff];
          acc[it] = __builtin_amdgcn_mfma_f32_16x16x32_bf16(wf, af, acc[it], 0, 0, 0);
        }
      }
    }
    __builtin_amdgcn_s_setprio(0);
  }

  if (MODE == 0) {
    float* out = (float*)outv;
#pragma unroll
    for (int nt = 0; nt < 4; ++nt) {
      float bn = bias[n0 + (nt << 4) + m16];
#pragma unroll
      for (int r = 0; r < 4; ++r) {
        int i = i0 + (wave << 4) + (quad << 2) + r;
        out[(size_t)i * 512 + n0 + (nt << 4) + m16] = acc[nt][r] + bn;
      }
    }
  } else {  // MODE 1: Vt [bh][d][l], masked columns -> 0
    ushort* out = (ushort*)outv;
    const int b = i0 >> 11, l0 = i0 & 2047, h = n0 >> 6;
    float4 b4 = *(const float4*)(bias + n0 + (wave << 4) + (quad << 2));
    float bb[4] = {b4.x, b4.y, b4.z, b4.w};
    float mkf[4];
#pragma unroll
    for (int it = 0; it < 4; ++it)
      mkf[it] = (mvec[b * 2048 + l0 + (it << 4) + m16] != 0) ? 1.f : 0.f;
#pragma unroll
    for (int r = 0; r < 4; ++r) {
      int d = (wave << 4) + (quad << 2) + r;
#pragma unroll
      for (int it = 0; it < 4; ++it) {
        out[((size_t)(b * 8 + h) * 64 + d) * 2048 + l0 + (it << 4) + m16] =
            f2bf((acc[it][r] + bb[r]) * mkf[it]);
      }
    }
  }
}

template <int MODE, int AFP32>
__global__ __launch_bounds__(256) void gemm_tile(const void* __restrict__ A,
                                                 const ushort* __restrict__ Wt,
                                                 const float* __restrict__ bias,
                                                 void* __restrict__ outv) {
  gemm_tile_body<MODE, AFP32>(A, Wt, bias, nullptr, outv, blockIdx.x,
                              blockIdx.y, 1.f);
}

// ============================================================================
// gemm_qk128: BM=128 x BN=64 tile, BK=64, fused fp32->bf16 A staging, MODE-2
// output (bf16 head-split [bh][l][d], scaled). 16 MFMA per wave-K-step.
// ============================================================================
__device__ __forceinline__ void gemm_qk128(const float* __restrict__ A,
                                           const ushort* __restrict__ Wt,
                                           const float* __restrict__ bias,
                                           ushort* __restrict__ out,
                                           int bx, int by, float oscale) {
  __shared__ ushort As[128 * LDT];
  __shared__ ushort Bs[64 * LDT];
  const int t = threadIdx.x;
  const int lane = t & 63, wave = t >> 6;
  const int m16 = lane & 15, quad = lane >> 4;
  const int koff = quad << 3;
  const int i0 = by * 128, n0 = bx * 64;
  const float* Ab = A + (size_t)i0 * 512;
  const ushort* Bb = Wt + (size_t)n0 * 512;

  // staging maps: A 128x64 (4 chunks/thread), B 64x64 (2 chunks/thread)
  int arow[4], acol[4];
#pragma unroll
  for (int s = 0; s < 4; ++s) {
    int idx = t + s * 256;
    arow[s] = idx >> 3;
    acol[s] = (idx & 7) << 3;
  }
  const int brow0 = t >> 3, bcol0 = (t & 7) << 3;
  const int brow1 = (t + 256) >> 3, bcol1 = ((t + 256) & 7) << 3;

  float4 afA[4], afB[4];
  uint4 br0, br1;
#pragma unroll
  for (int s = 0; s < 4; ++s) {
    afA[s] = *(const float4*)(Ab + (size_t)arow[s] * 512 + acol[s]);
    afB[s] = *(const float4*)(Ab + (size_t)arow[s] * 512 + acol[s] + 4);
  }
  br0 = *(const uint4*)(Bb + (size_t)brow0 * 512 + bcol0);
  br1 = *(const uint4*)(Bb + (size_t)brow1 * 512 + bcol1);

  f32x4 acc[2][4];
#pragma unroll
  for (int mi = 0; mi < 2; ++mi)
#pragma unroll
    for (int nt = 0; nt < 4; ++nt) acc[mi][nt] = (f32x4){0.f, 0.f, 0.f, 0.f};

  for (int ks = 0; ks < 8; ++ks) {
    __syncthreads();
#pragma unroll
    for (int s = 0; s < 4; ++s)
      *(bf16x8*)&As[arow[s] * LDT + acol[s]] = pack8(afA[s], afB[s]);
    *(uint4*)&Bs[brow0 * LDT + bcol0] = br0;
    *(uint4*)&Bs[brow1 * LDT + bcol1] = br1;
    __syncthreads();

    const int kn = ((ks + 1) & 7) << 6;
#pragma unroll
    for (int s = 0; s < 4; ++s) {
      afA[s] = *(const float4*)(Ab + (size_t)arow[s] * 512 + kn + acol[s]);
      afB[s] = *(const float4*)(Ab + (size_t)arow[s] * 512 + kn + acol[s] + 4);
    }
    br0 = *(const uint4*)(Bb + (size_t)brow0 * 512 + kn + bcol0);
    br1 = *(const uint4*)(Bb + (size_t)brow1 * 512 + kn + bcol1);

    __builtin_amdgcn_s_setprio(1);
#pragma unroll
    for (int kh = 0; kh < 2; ++kh) {
      bf16x8 af0 = *(const bf16x8*)&As[((wave << 5) + m16) * LDT + (kh << 5) + koff];
      bf16x8 af1 = *(const bf16x8*)&As[((wave << 5) + 16 + m16) * LDT + (kh << 5) + koff];
#pragma unroll
      for (int nt = 0; nt < 4; ++nt) {
        bf16x8 wf = *(const bf16x8*)&Bs[((nt << 4) + m16) * LDT + (kh << 5) + koff];
        acc[0][nt] = __builtin_amdgcn_mfma_f32_16x16x32_bf16(af0, wf, acc[0][nt], 0, 0, 0);
        acc[1][nt] = __builtin_amdgcn_mfma_f32_16x16x32_bf16(af1, wf, acc[1][nt], 0, 0, 0);
      }
    }
    __builtin_amdgcn_s_setprio(0);
  }

  const int b = i0 >> 11, l0 = i0 & 2047, h = n0 >> 6;
#pragma unroll
  for (int nt = 0; nt < 4; ++nt) {
    float bn = bias[n0 + (nt << 4) + m16];
    int d = (nt << 4) + m16;
#pragma unroll
    for (int mi = 0; mi < 2; ++mi) {
#pragma unroll
      for (int r = 0; r < 4; ++r) {
        int il = (wave << 5) + (mi << 4) + (quad << 2) + r;
        out[((size_t)(b * 8 + h) * 2048 + l0 + il) * 64 + d] =
            f2bf((acc[mi][nt][r] + bn) * oscale);
      }
    }
  }
}

// Merged QKV projection. Grid (8, 32, 3). z=0/1: Q/K via 128-row tiles;
// z=2: V via two sequential 64-row MODE-1 tiles (balanced work per block).
// Q output pre-scaled by 0.125 (exact in bf16).
__global__ __launch_bounds__(256) void gemm_qkv(
    const float* __restrict__ q, const float* __restrict__ k,
    const float* __restrict__ v, const ushort* __restrict__ Wt,
    const float* __restrict__ bq, const float* __restrict__ bk,
    const float* __restrict__ bv, const int* __restrict__ mask,
    ushort* __restrict__ Qw, ushort* __restrict__ Kw, ushort* __restrict__ Vtw) {
  const int z = blockIdx.z;
  if (z == 0) {
    gemm_qk128(q, Wt, bq, Qw, blockIdx.x, blockIdx.y, 0.125f);
  } else if (z == 1) {
    gemm_qk128(k, Wt + 262144, bk, Kw, blockIdx.x, blockIdx.y, 1.f);
  } else {
#pragma unroll
    for (int s = 0; s < 2; ++s)
      gemm_tile_body<1, 1>(v, Wt + 2 * 262144, bv, mask, (void*)Vtw,
                           blockIdx.x, blockIdx.y * 2 + s, 1.f);
  }
}

// ============================================================================
// qrel_tile: qrelh[bh][i][r] (fp16, stride 504) = sum_d Q[bh][i][d]*rel8[r][d].
// LDS-tiled single-K-step GEMM; epilogue repacks acc through LDS so each
// thread does 2 coalesced b128 stores (128-B runs) instead of 16 b16 stores.
// Grid (8, 32, 16).
// ============================================================================
__global__ __launch_bounds__(256) void qrel_tile(const ushort* __restrict__ Qw,
                                                 const ushort* __restrict__ rel8,
                                                 ushort* __restrict__ qrelh) {
  __shared__ ushort As[64 * LDT];
  __shared__ ushort Bs[64 * LDT];
  const int t = threadIdx.x;
  const int lane = t & 63, wave = t >> 6;
  const int m16 = lane & 15, quad = lane >> 4;
  const int koff = quad << 3;
  const int r0 = blockIdx.x * 64;
  const int i0 = blockIdx.y * 64;
  const int bh = blockIdx.z;
  const int row0 = t >> 3, off0 = (t & 7) << 3;
  const int row1 = (t + 256) >> 3, off1 = ((t + 256) & 7) << 3;

  *(uint4*)&As[row0 * LDT + off0] =
      *(const uint4*)(Qw + ((size_t)bh * 2048 + i0 + row0) * 64 + off0);
  *(uint4*)&As[row1 * LDT + off1] =
      *(const uint4*)(Qw + ((size_t)bh * 2048 + i0 + row1) * 64 + off1);
  *(uint4*)&Bs[row0 * LDT + off0] =
      *(const uint4*)(rel8 + (size_t)(r0 + row0) * 64 + off0);
  *(uint4*)&Bs[row1 * LDT + off1] =
      *(const uint4*)(rel8 + (size_t)(r0 + row1) * 64 + off1);
  __syncthreads();

  f32x4 acc[4] = {{0.f, 0.f, 0.f, 0.f}, {0.f, 0.f, 0.f, 0.f},
                  {0.f, 0.f, 0.f, 0.f}, {0.f, 0.f, 0.f, 0.f}};
#pragma unroll
  for (int kh = 0; kh < 2; ++kh) {
    bf16x8 af = *(const bf16x8*)&As[((wave << 4) + m16) * LDT + (kh << 5) + koff];
#pragma unroll
    for (int nt = 0; nt < 4; ++nt) {
      bf16x8 wf = *(const bf16x8*)&Bs[((nt << 4) + m16) * LDT + (kh << 5) + koff];
      acc[nt] = __builtin_amdgcn_mfma_f32_16x16x32_bf16(af, wf, acc[nt], 0, 0, 0);
    }
  }

  // ---- repack: acc -> LDS fp16 [i_local][r_local] (stride LDT) ----
  __syncthreads();  // all As/Bs reads done; reuse As
#pragma unroll
  for (int nt = 0; nt < 4; ++nt) {
#pragma unroll
    for (int rg = 0; rg < 4; ++rg) {
      int il = (wave << 4) + (quad << 2) + rg;
      As[il * LDT + (nt << 4) + m16] = f2h(acc[nt][rg]);
    }
  }
  __syncthreads();

  // coalesced stores: thread t -> row t>>2, 16 ushorts at chunk (t&3)*16
  const int orow = t >> 2, och = (t & 3) << 4;
  uint4 s0 = *(const uint4*)&As[orow * LDT + och];
  uint4 s1 = *(const uint4*)&As[orow * LDT + och + 8];
  ushort* dst = qrelh + ((size_t)bh * 2048 + i0 + orow) * NREL_PAD + r0 + och;
  *(uint4*)dst = s0;  // r0+och+7 <= 503 always (r0<=448, och<=48)
  if (r0 + och + 15 < NREL_PAD) *(uint4*)(dst + 8) = s1;
}

// ============================================================================
// qrel gather (fp16 table) for one 64-j tile; wave-uniform clamp shortcut
// with hoisted edge values (zero loads on fully-clamped tiles).
// ============================================================================
__device__ __forceinline__ void gather_qv(float qv[4][4],
                                          const ushort* __restrict__ qrow,
                                          float e_lo, float e_hi,
                                          int iq, int iw0, int j0, int quad) {
  if (j0 - iw0 >= 264) {
#pragma unroll
    for (int jt = 0; jt < 4; ++jt)
#pragma unroll
      for (int r = 0; r < 4; ++r) qv[jt][r] = e_hi;
  } else if (iw0 - j0 >= 312) {
#pragma unroll
    for (int jt = 0; jt < 4; ++jt)
#pragma unroll
      for (int r = 0; r < 4; ++r) qv[jt][r] = e_lo;
  } else {
#pragma unroll
    for (int jt = 0; jt < 4; ++jt) {
#pragma unroll
      for (int r = 0; r < 4; ++r) {
        int j = j0 + (jt << 4) + (quad << 2) + r;
        int rr = min(NREL - 1, max(0, j - iq + 249));
        qv[jt][r] = h2f(qrow[rr]);
      }
    }
  }
}

// ============================================================================
// Flash attention (R6/R9 structure, frozen): LDS-staged K/V, register
// prefetch, swapped-operand QK^T with bias-initialized C, in-register
// softmax, defer-max, MFMA l-accumulation, XCD swizzle, 2x unroll.
// ============================================================================
__global__ __launch_bounds__(256) void flash_attn(
    const ushort* __restrict__ Qw, const ushort* __restrict__ Kw,
    const ushort* __restrict__ Vt, const ushort* __restrict__ qrelh,
    const ushort* __restrict__ maskbf, ushort* __restrict__ attnbf) {
  __shared__ ushort QPs[64 * LDB];  // Q tile [i][d]; later P [i][j]
  __shared__ ushort Ks[64 * LDB];   // [j][d]
  __shared__ ushort Vs[64 * LDB];   // [d][j]
  const int t = threadIdx.x;
  const int lane = t & 63, wave = t >> 6;
  const int m16 = lane & 15, quad = lane >> 4;
  const int koff = quad << 3;
  const int bid = ((int)blockIdx.y << 5) + (int)blockIdx.x;
  const int swz = ((bid & 7) << 6) + (bid >> 3);  // XCD-contiguous chunks
  const int i0 = (swz & 31) << 6;
  const int bh = swz >> 5;
  const int b = bh >> 3, h = bh & 7;
  const ushort* Qb = Qw + (size_t)bh * 2048 * 64;
  const ushort* Kb = Kw + (size_t)bh * 2048 * 64;
  const ushort* Vb = Vt + (size_t)bh * 64 * 2048;
  const ushort* mbf = maskbf + b * 2048;
  const int iw0 = i0 + (wave << 4);
  const int iq = iw0 + m16;  // this lane's output row
  const ushort* qrow = qrelh + ((size_t)bh * 2048 + iq) * NREL_PAD;
  const float e_lo = h2f(qrow[0]), e_hi = h2f(qrow[NREL - 1]);

  const int row0 = t >> 3, off0 = (t & 7) << 3;
  const int row1 = (t + 256) >> 3, off1 = ((t + 256) & 7) << 3;

  // Q tile -> LDS
  *(uint4*)&QPs[row0 * LDB + off0] =
      *(const uint4*)(Qb + (size_t)(i0 + row0) * 64 + off0);
  *(uint4*)&QPs[row1 * LDB + off1] =
      *(const uint4*)(Qb + (size_t)(i0 + row1) * 64 + off1);
  __syncthreads();

  bf16x8 qa0 = *(const bf16x8*)&QPs[((wave << 4) + m16) * LDB + koff];
  bf16x8 qa1 = *(const bf16x8*)&QPs[((wave << 4) + m16) * LDB + 32 + koff];

  float m_i = -INFINITY;
  f32x4 oacc[4];
  f32x4 lacc = {0.f, 0.f, 0.f, 0.f};
#pragma unroll
  for (int dt = 0; dt < 4; ++dt) oacc[dt] = (f32x4){0.f, 0.f, 0.f, 0.f};

  // ---- prologue prefetch (set A) for j0 = 0 ----
  uint4 krA0 = *(const uint4*)(Kb + (size_t)row0 * 64 + off0);
  uint4 krA1 = *(const uint4*)(Kb + (size_t)row1 * 64 + off1);
  uint4 vrA0 = *(const uint4*)(Vb + (size_t)row0 * 2048 + off0);
  uint4 vrA1 = *(const uint4*)(Vb + (size_t)row1 * 2048 + off1);
  bf16x8 mfA0 = *(const bf16x8*)(mbf + koff);
  bf16x8 mfA1 = *(const bf16x8*)(mbf + 32 + koff);
  float qvA[4][4];
  gather_qv(qvA, qrow, e_lo, e_hi, iq, iw0, 0, quad);
  uint4 krB0, krB1, vrB0, vrB1;
  bf16x8 mfB0, mfB1;
  float qvB[4][4];

#define FLASH_STEP(KR0, KR1, VR0, VR1, MF0, MF1, QV,                          \
                   KN0, KN1, VN0, VN1, MG0, MG1, QN, JN)                      \
  do {                                                                        \
    __syncthreads();                                                          \
    *(uint4*)&Ks[row0 * LDB + off0] = KR0;                                    \
    *(uint4*)&Ks[row1 * LDB + off1] = KR1;                                    \
    *(uint4*)&Vs[row0 * LDB + off0] = VR0;                                    \
    *(uint4*)&Vs[row1 * LDB + off1] = VR1;                                    \
    __syncthreads();                                                          \
    KN0 = *(const uint4*)(Kb + (size_t)((JN) + row0) * 64 + off0);            \
    KN1 = *(const uint4*)(Kb + (size_t)((JN) + row1) * 64 + off1);            \
    VN0 = *(const uint4*)(Vb + (size_t)row0 * 2048 + (JN) + off0);            \
    VN1 = *(const uint4*)(Vb + (size_t)row1 * 2048 + (JN) + off1);            \
    MG0 = *(const bf16x8*)(mbf + (JN) + koff);                                \
    MG1 = *(const bf16x8*)(mbf + (JN) + 32 + koff);                           \
    gather_qv(QN, qrow, e_lo, e_hi, iq, iw0, (JN), quad);                     \
    f32x4 sacc[4];                                                            \
    __builtin_amdgcn_s_setprio(1);                                            \
    _Pragma("unroll")                                                         \
    for (int jt = 0; jt < 4; ++jt) {                                          \
      bf16x8 kf0 = *(const bf16x8*)&Ks[((jt << 4) + m16) * LDB + koff];       \
      bf16x8 kf1 = *(const bf16x8*)&Ks[((jt << 4) + m16) * LDB + 32 + koff];  \
      f32x4 z = {QV[jt][0], QV[jt][1], QV[jt][2], QV[jt][3]};                 \
      z = __builtin_amdgcn_mfma_f32_16x16x32_bf16(kf0, qa0, z, 0, 0, 0);      \
      z = __builtin_amdgcn_mfma_f32_16x16x32_bf16(kf1, qa1, z, 0, 0, 0);      \
      sacc[jt] = z;                                                           \
    }                                                                         \
    __builtin_amdgcn_s_setprio(0);                                            \
    float t0 = fmaxf(fmaxf(sacc[0][0], sacc[0][1]),                           \
                     fmaxf(sacc[0][2], sacc[0][3]));                          \
    float t1 = fmaxf(fmaxf(sacc[1][0], sacc[1][1]),                           \
                     fmaxf(sacc[1][2], sacc[1][3]));                          \
    float t2 = fmaxf(fmaxf(sacc[2][0], sacc[2][1]),                           \
                     fmaxf(sacc[2][2], sacc[2][3]));                          \
    float t3 = fmaxf(fmaxf(sacc[3][0], sacc[3][1]),                           \
                     fmaxf(sacc[3][2], sacc[3][3]));                          \
    float mx = fmaxf(fmaxf(t0, t1), fmaxf(t2, t3));                           \
    mx = fmaxf(mx, __shfl_xor(mx, 16));                                       \
    mx = fmaxf(mx, __shfl_xor(mx, 32));                                       \
    if (__any(mx > m_i + 8.f)) {                                              \
      float mnew = fmaxf(m_i, mx);                                            \
      float al = __expf(m_i - mnew);                                          \
      m_i = mnew;                                                             \
      _Pragma("unroll")                                                       \
      for (int dt = 0; dt < 4; ++dt) {                                        \
        oacc[dt][0] *= al; oacc[dt][1] *= al;                                 \
        oacc[dt][2] *= al; oacc[dt][3] *= al;                                 \
      }                                                                       \
      lacc[0] *= al; lacc[1] *= al; lacc[2] *= al; lacc[3] *= al;             \
    }                                                                         \
    const int prow = ((wave << 4) + m16) * LDB;                               \
    _Pragma("unroll")                                                         \
    for (int jt = 0; jt < 4; ++jt) {                                          \
      ushort4 pk;                                                             \
      pk.x = f2bf(__expf(sacc[jt][0] - m_i));                                 \
      pk.y = f2bf(__expf(sacc[jt][1] - m_i));                                 \
      pk.z = f2bf(__expf(sacc[jt][2] - m_i));                                 \
      pk.w = f2bf(__expf(sacc[jt][3] - m_i));                                 \
      *(ushort4*)&QPs[prow + (jt << 4) + (quad << 2)] = pk;                   \
    }                                                                         \
    __asm__ volatile("s_waitcnt lgkmcnt(0)" ::: "memory");                    \
    bf16x8 pa0 = *(const bf16x8*)&QPs[prow + koff];                           \
    bf16x8 pa1 = *(const bf16x8*)&QPs[prow + 32 + koff];                      \
    __builtin_amdgcn_s_setprio(1);                                            \
    lacc = __builtin_amdgcn_mfma_f32_16x16x32_bf16(MF0, pa0, lacc, 0, 0, 0);  \
    lacc = __builtin_amdgcn_mfma_f32_16x16x32_bf16(MF1, pa1, lacc, 0, 0, 0);  \
    _Pragma("unroll")                                                         \
    for (int dt = 0; dt < 4; ++dt) {                                          \
      bf16x8 vf0 = *(const bf16x8*)&Vs[((dt << 4) + m16) * LDB + koff];       \
      bf16x8 vf1 = *(const bf16x8*)&Vs[((dt << 4) + m16) * LDB + 32 + koff];  \
      oacc[dt] =                                                              \
          __builtin_amdgcn_mfma_f32_16x16x32_bf16(vf0, pa0, oacc[dt], 0, 0, 0); \
      oacc[dt] =                                                              \
          __builtin_amdgcn_mfma_f32_16x16x32_bf16(vf1, pa1, oacc[dt], 0, 0, 0); \
    }                                                                         \
    __builtin_amdgcn_s_setprio(0);                                            \
  } while (0)

  for (int j0 = 0; j0 < 2048; j0 += 128) {
    FLASH_STEP(krA0, krA1, vrA0, vrA1, mfA0, mfA1, qvA,
               krB0, krB1, vrB0, vrB1, mfB0, mfB1, qvB, j0 + 64);
    FLASH_STEP(krB0, krB1, vrB0, vrB1, mfB0, mfB1, qvB,
               krA0, krA1, vrA0, vrA1, mfA0, mfA1, qvA, (j0 + 128) & 2047);
  }
#undef FLASH_STEP

  // epilogue: lane holds O[iq][d = dt*16 + quad*4 + r]; l = lacc[0]
  float inv = 1.0f / lacc[0];
  ushort* dst = attnbf + (size_t)(b * 2048 + iq) * 512 + h * 64;
#pragma unroll
  for (int dt = 0; dt < 4; ++dt) {
    ushort4 st;
    st.x = f2bf(oacc[dt][0] * inv);
    st.y = f2bf(oacc[dt][1] * inv);
    st.z = f2bf(oacc[dt][2] * inv);
    st.w = f2bf(oacc[dt][3] * inv);
    *(ushort4*)(dst + (dt << 4) + (quad << 2)) = st;
  }
}

// ============================================================================
extern "C" void kernel_launch(void* const* d_in, const int* in_sizes, int n_in,
                              void* d_out, int out_size, void* d_ws,
                              size_t ws_size, hipStream_t stream) {
  const float* query = (const float*)d_in[0];
  const float* key   = (const float*)d_in[1];
  const float* value = (const float*)d_in[2];
  const int*   mask  = (const int*)d_in[3];
  const float* Wq = (const float*)d_in[4];
  const float* bq = (const float*)d_in[5];
  const float* Wk = (const float*)d_in[6];
  const float* bk = (const float*)d_in[7];
  const float* Wv = (const float*)d_in[8];
  const float* bv = (const float*)d_in[9];
  const float* Wo = (const float*)d_in[10];
  const float* bo = (const float*)d_in[11];
  const float* rel = (const float*)d_in[12];

  char* w = (char*)d_ws;
  size_t off = 0;
  ushort* Qw  = (ushort*)(w + off); off += (size_t)16 * 2048 * 64 * 2;       // 4 MB
  ushort* Kw  = (ushort*)(w + off); off += (size_t)16 * 2048 * 64 * 2;       // 4 MB
  ushort* Vtw = (ushort*)(w + off); off += (size_t)16 * 64 * 2048 * 2;       // 4 MB
  ushort* Wt  = (ushort*)(w + off); off += (size_t)4 * 512 * 512 * 2;        // 2 MB
  ushort* qrelh = (ushort*)(w + off); off += (size_t)16 * 2048 * NREL_PAD * 2; // 33 MB
  ushort* attnbf = (ushort*)(w + off); off += (size_t)4096 * 512 * 2;        // 4 MB
  ushort* maskbf = (ushort*)(w + off); off += (size_t)2 * 2048 * 2;          // 8 KB
  ushort* rel8 = (ushort*)(w + off); off += (size_t)512 * 64 * 2;            // 64 KB
  float* out = (float*)d_out;

  dim3 bb(256);
  hipLaunchKernelGGL(prep_wt, dim3(8, 8, 4), bb, 0, stream, Wq, Wk, Wv, Wo,
                     mask, rel, Wt, maskbf, rel8);
  hipLaunchKernelGGL(gemm_qkv, dim3(8, 32, 3), bb, 0, stream, query, key, value,
                     Wt, bq, bk, bv, mask, Qw, Kw, Vtw);
  hipLaunchKernelGGL(qrel_tile, dim3(8, 32, 16), bb, 0, stream, Qw, rel8, qrelh);
  hipLaunchKernelGGL(flash_attn, dim3(32, 16), bb, 0, stream, Qw, Kw, Vtw,
                     qrelh, maskbf, attnbf);
  hipLaunchKernelGGL((gemm_tile<0, 0>), dim3(8, 64), bb, 0, stream, attnbf,
                     Wt + 3 * 262144, bo, (void*)out);
}

// Round 14
// 205.512 us; speedup vs baseline: 1.0405x; 1.0405x over previous
//
#include <hip/hip_runtime.h>
#include <math.h>

// Problem constants
#define NREL 499        // 2*MAX_LEN-1
#define NREL_PAD 504    // fp16 row stride (1008 B, 16-B aligned)
#define LDB 72          // bf16 LDS row stride (flash kernel)
#define LDT 72          // bf16 LDS row stride (gemm tiles)

typedef __attribute__((ext_vector_type(8))) short bf16x8;
typedef __attribute__((ext_vector_type(4))) float f32x4;

__device__ __forceinline__ float bf2f(ushort x) {
  union { unsigned u; float f; } v; v.u = ((unsigned)x) << 16; return v.f;
}
__device__ __forceinline__ ushort f2bf(float x) {
  union { float f; unsigned u; } v; v.f = x;
  return (ushort)((v.u + 0x8000u) >> 16);
}
__device__ __forceinline__ ushort f2h(float x) {
  union { _Float16 h; ushort u; } v; v.h = (_Float16)x; return v.u;
}
__device__ __forceinline__ float h2f(ushort u) {
  union { _Float16 h; ushort u; } v; v.u = u; return (float)v.h;
}
__device__ __forceinline__ bf16x8 pack8(float4 a, float4 b) {
  bf16x8 r;
  r[0] = (short)f2bf(a.x); r[1] = (short)f2bf(a.y);
  r[2] = (short)f2bf(a.z); r[3] = (short)f2bf(a.w);
  r[4] = (short)f2bf(b.x); r[5] = (short)f2bf(b.y);
  r[6] = (short)f2bf(b.z); r[7] = (short)f2bf(b.w);
  return r;
}

// ============================================================================
// prep_wt: Wt[z][n][k] (bf16) = W_z[k][n], z = {q,k,v,o}. Grid (8,8,4).
// Blocks (0,0,z): build maskbf[b][j] = mask ? 1.0bf : 0.0bf.
// Blocks (1,0,z): build rel8[512][64] bf16 = 8 * rel (rows >= 499 zeroed).
// ============================================================================
__global__ __launch_bounds__(256) void prep_wt(const float* __restrict__ W0,
                                               const float* __restrict__ W1,
                                               const float* __restrict__ W2,
                                               const float* __restrict__ W3,
                                               const int* __restrict__ mask,
                                               const float* __restrict__ rel,
                                               ushort* __restrict__ Wt,
                                               ushort* __restrict__ maskbf,
                                               ushort* __restrict__ rel8) {
  __shared__ float T[64][68];
  const int t = threadIdx.x;
  const int k0 = blockIdx.x * 64, n0 = blockIdx.y * 64, z = blockIdx.z;
  const float* W = (z == 0) ? W0 : (z == 1) ? W1 : (z == 2) ? W2 : W3;
#pragma unroll
  for (int s = 0; s < 4; ++s) {
    int idx = t + s * 256;
    int r = idx >> 4, c4 = (idx & 15) << 2;
    *(float4*)&T[r][c4] = *(const float4*)(W + (size_t)(k0 + r) * 512 + n0 + c4);
  }
  if (blockIdx.x == 0 && blockIdx.y == 0) {
    int base = z * 1024 + t * 4;
    int4 mv = *(const int4*)(mask + base);
    ushort4 mo;
    mo.x = mv.x ? 0x3F80 : 0; mo.y = mv.y ? 0x3F80 : 0;
    mo.z = mv.z ? 0x3F80 : 0; mo.w = mv.w ? 0x3F80 : 0;
    *(ushort4*)(maskbf + base) = mo;
  } else if (blockIdx.x == 1 && blockIdx.y == 0) {
    int base = z * 8192 + t * 32;
#pragma unroll
    for (int c = 0; c < 4; ++c) {
      int e0 = base + c * 8;
      ushort tmp[8];
#pragma unroll
      for (int k = 0; k < 8; ++k) {
        int e = e0 + k;
        float v = (e < NREL * 64) ? rel[e] * 8.f : 0.f;
        tmp[k] = f2bf(v);
      }
      *(ushort4*)(rel8 + e0) = make_ushort4(tmp[0], tmp[1], tmp[2], tmp[3]);
      *(ushort4*)(rel8 + e0 + 4) = make_ushort4(tmp[4], tmp[5], tmp[6], tmp[7]);
    }
  }
  __syncthreads();
#pragma unroll
  for (int s = 0; s < 4; ++s) {
    int idx = t + s * 256;
    int row = idx >> 4, c4 = (idx & 15) << 2;  // row = n_local, c4 = k_local
    ushort4 u = make_ushort4(f2bf(T[c4 + 0][row]), f2bf(T[c4 + 1][row]),
                             f2bf(T[c4 + 2][row]), f2bf(T[c4 + 3][row]));
    *(ushort4*)(Wt + (size_t)z * 262144 + (size_t)(n0 + row) * 512 + k0 + c4) = u;
  }
}

// ============================================================================
// gemm_tile_body (64x64): C = A @ Wt^T + bias. Proven R4 structure.
// AFP32=1: A fp32 cast to bf16 during staging.
// MODE 0: fp32 row-major out; MODE 1: bf16 Vt [bh][d][l] masked-zeroed.
// ============================================================================
template <int MODE, int AFP32>
__device__ __forceinline__ void gemm_tile_body(const void* __restrict__ Av,
                                               const ushort* __restrict__ Wt,
                                               const float* __restrict__ bias,
                                               const int* __restrict__ mvec,
                                               void* __restrict__ outv,
                                               int bx, int by, float oscale) {
  __shared__ ushort As[64 * LDT];
  __shared__ ushort Bs[64 * LDT];
  const int t = threadIdx.x;
  const int lane = t & 63, wave = t >> 6;
  const int m16 = lane & 15, quad = lane >> 4;
  const int koff = quad << 3;
  const int i0 = by * 64, n0 = bx * 64;
  const int row0 = t >> 3, off0 = (t & 7) << 3;
  const int row1 = (t + 256) >> 3, off1 = ((t + 256) & 7) << 3;
  const ushort* Ab16 = (const ushort*)Av + (size_t)i0 * 512;
  const float*  Ab32 = (const float*)Av + (size_t)i0 * 512;
  const ushort* Bb = Wt + (size_t)n0 * 512;

  uint4 ar0, ar1;
  float4 af00, af01, af10, af11;
  if (AFP32) {
    af00 = *(const float4*)(Ab32 + (size_t)row0 * 512 + off0);
    af01 = *(const float4*)(Ab32 + (size_t)row0 * 512 + off0 + 4);
    af10 = *(const float4*)(Ab32 + (size_t)row1 * 512 + off1);
    af11 = *(const float4*)(Ab32 + (size_t)row1 * 512 + off1 + 4);
  } else {
    ar0 = *(const uint4*)(Ab16 + (size_t)row0 * 512 + off0);
    ar1 = *(const uint4*)(Ab16 + (size_t)row1 * 512 + off1);
  }
  uint4 br0 = *(const uint4*)(Bb + (size_t)row0 * 512 + off0);
  uint4 br1 = *(const uint4*)(Bb + (size_t)row1 * 512 + off1);

  f32x4 acc[4] = {{0.f, 0.f, 0.f, 0.f}, {0.f, 0.f, 0.f, 0.f},
                  {0.f, 0.f, 0.f, 0.f}, {0.f, 0.f, 0.f, 0.f}};

  for (int ks = 0; ks < 8; ++ks) {
    __syncthreads();
    if (AFP32) {
      *(bf16x8*)&As[row0 * LDT + off0] = pack8(af00, af01);
      *(bf16x8*)&As[row1 * LDT + off1] = pack8(af10, af11);
    } else {
      *(uint4*)&As[row0 * LDT + off0] = ar0;
      *(uint4*)&As[row1 * LDT + off1] = ar1;
    }
    *(uint4*)&Bs[row0 * LDT + off0] = br0;
    *(uint4*)&Bs[row1 * LDT + off1] = br1;
    __syncthreads();

    const int kn = ((ks + 1) & 7) << 6;
    if (AFP32) {
      af00 = *(const float4*)(Ab32 + (size_t)row0 * 512 + kn + off0);
      af01 = *(const float4*)(Ab32 + (size_t)row0 * 512 + kn + off0 + 4);
      af10 = *(const float4*)(Ab32 + (size_t)row1 * 512 + kn + off1);
      af11 = *(const float4*)(Ab32 + (size_t)row1 * 512 + kn + off1 + 4);
    } else {
      ar0 = *(const uint4*)(Ab16 + (size_t)row0 * 512 + kn + off0);
      ar1 = *(const uint4*)(Ab16 + (size_t)row1 * 512 + kn + off1);
    }
    br0 = *(const uint4*)(Bb + (size_t)row0 * 512 + kn + off0);
    br1 = *(const uint4*)(Bb + (size_t)row1 * 512 + kn + off1);

    __builtin_amdgcn_s_setprio(1);
    if (MODE != 1) {
#pragma unroll
      for (int kh = 0; kh < 2; ++kh) {
        bf16x8 af = *(const bf16x8*)&As[((wave << 4) + m16) * LDT + (kh << 5) + koff];
#pragma unroll
        for (int nt = 0; nt < 4; ++nt) {
          bf16x8 wf = *(const bf16x8*)&Bs[((nt << 4) + m16) * LDT + (kh << 5) + koff];
          acc[nt] = __builtin_amdgcn_mfma_f32_16x16x32_bf16(af, wf, acc[nt], 0, 0, 0);
        }
      }
    } else {
#pragma unroll
      for (int kh = 0; kh < 2; ++kh) {
        bf16x8 wf = *(const bf16x8*)&Bs[((wave << 4) + m16) * LDT + (kh << 5) + koff];
#pragma unroll
        for (int it = 0; it < 4; ++it) {
          bf16x8 af = *(const bf16x8*)&As[((it << 4) + m16) * LDT + (kh << 5) + koff];
          acc[it] = __builtin_amdgcn_mfma_f32_16x16x32_bf16(wf, af, acc[it], 0, 0, 0);
        }
      }
    }
    __builtin_amdgcn_s_setprio(0);
  }

  if (MODE == 0) {
    float* out = (float*)outv;
#pragma unroll
    for (int nt = 0; nt < 4; ++nt) {
      float bn = bias[n0 + (nt << 4) + m16];
#pragma unroll
      for (int r = 0; r < 4; ++r) {
        int i = i0 + (wave << 4) + (quad << 2) + r;
        out[(size_t)i * 512 + n0 + (nt << 4) + m16] = acc[nt][r] + bn;
      }
    }
  } else {  // MODE 1: Vt [bh][d][l], masked columns -> 0
    ushort* out = (ushort*)outv;
    const int b = i0 >> 11, l0 = i0 & 2047, h = n0 >> 6;
    float4 b4 = *(const float4*)(bias + n0 + (wave << 4) + (quad << 2));
    float bb[4] = {b4.x, b4.y, b4.z, b4.w};
    float mkf[4];
#pragma unroll
    for (int it = 0; it < 4; ++it)
      mkf[it] = (mvec[b * 2048 + l0 + (it << 4) + m16] != 0) ? 1.f : 0.f;
#pragma unroll
    for (int r = 0; r < 4; ++r) {
      int d = (wave << 4) + (quad << 2) + r;
#pragma unroll
      for (int it = 0; it < 4; ++it) {
        out[((size_t)(b * 8 + h) * 64 + d) * 2048 + l0 + (it << 4) + m16] =
            f2bf((acc[it][r] + bb[r]) * mkf[it]);
      }
    }
  }
}

template <int MODE, int AFP32>
__global__ __launch_bounds__(256) void gemm_tile(const void* __restrict__ A,
                                                 const ushort* __restrict__ Wt,
                                                 const float* __restrict__ bias,
                                                 void* __restrict__ outv) {
  gemm_tile_body<MODE, AFP32>(A, Wt, bias, nullptr, outv, blockIdx.x,
                              blockIdx.y, 1.f);
}

// ============================================================================
// gemm_qk128: BM=128 x BN=64 tile, BK=64, fused fp32->bf16 A staging, MODE-2
// output (bf16 head-split [bh][l][d], scaled). QREL=1 additionally computes
// qrelh[bh][l][r] = Qrow . rel8[r] for the block's 128 rows x all 512 r,
// reusing the in-register Q tile (repacked via As; wave-local rows so no
// barrier, only lgkmcnt). Bit-identical to the old separate qrel_tile.
// ============================================================================
template <int QREL>
__device__ __forceinline__ void gemm_qk128(const float* __restrict__ A,
                                           const ushort* __restrict__ Wt,
                                           const float* __restrict__ bias,
                                           ushort* __restrict__ out,
                                           const ushort* __restrict__ rel8,
                                           ushort* __restrict__ qrelh,
                                           int bx, int by, float oscale) {
  __shared__ ushort As[128 * LDT];
  __shared__ ushort Bs[64 * LDT];
  const int t = threadIdx.x;
  const int lane = t & 63, wave = t >> 6;
  const int m16 = lane & 15, quad = lane >> 4;
  const int koff = quad << 3;
  const int i0 = by * 128, n0 = bx * 64;
  const float* Ab = A + (size_t)i0 * 512;
  const ushort* Bb = Wt + (size_t)n0 * 512;

  int arow[4], acol[4];
#pragma unroll
  for (int s = 0; s < 4; ++s) {
    int idx = t + s * 256;
    arow[s] = idx >> 3;
    acol[s] = (idx & 7) << 3;
  }
  const int brow0 = t >> 3, bcol0 = (t & 7) << 3;
  const int brow1 = (t + 256) >> 3, bcol1 = ((t + 256) & 7) << 3;

  float4 afA[4], afB[4];
  uint4 br0, br1;
#pragma unroll
  for (int s = 0; s < 4; ++s) {
    afA[s] = *(const float4*)(Ab + (size_t)arow[s] * 512 + acol[s]);
    afB[s] = *(const float4*)(Ab + (size_t)arow[s] * 512 + acol[s] + 4);
  }
  br0 = *(const uint4*)(Bb + (size_t)brow0 * 512 + bcol0);
  br1 = *(const uint4*)(Bb + (size_t)brow1 * 512 + bcol1);

  f32x4 acc[2][4];
#pragma unroll
  for (int mi = 0; mi < 2; ++mi)
#pragma unroll
    for (int nt = 0; nt < 4; ++nt) acc[mi][nt] = (f32x4){0.f, 0.f, 0.f, 0.f};

  for (int ks = 0; ks < 8; ++ks) {
    __syncthreads();
#pragma unroll
    for (int s = 0; s < 4; ++s)
      *(bf16x8*)&As[arow[s] * LDT + acol[s]] = pack8(afA[s], afB[s]);
    *(uint4*)&Bs[brow0 * LDT + bcol0] = br0;
    *(uint4*)&Bs[brow1 * LDT + bcol1] = br1;
    __syncthreads();

    const int kn = ((ks + 1) & 7) << 6;
#pragma unroll
    for (int s = 0; s < 4; ++s) {
      afA[s] = *(const float4*)(Ab + (size_t)arow[s] * 512 + kn + acol[s]);
      afB[s] = *(const float4*)(Ab + (size_t)arow[s] * 512 + kn + acol[s] + 4);
    }
    br0 = *(const uint4*)(Bb + (size_t)brow0 * 512 + kn + bcol0);
    br1 = *(const uint4*)(Bb + (size_t)brow1 * 512 + kn + bcol1);

    __builtin_amdgcn_s_setprio(1);
#pragma unroll
    for (int kh = 0; kh < 2; ++kh) {
      bf16x8 af0 = *(const bf16x8*)&As[((wave << 5) + m16) * LDT + (kh << 5) + koff];
      bf16x8 af1 = *(const bf16x8*)&As[((wave << 5) + 16 + m16) * LDT + (kh << 5) + koff];
#pragma unroll
      for (int nt = 0; nt < 4; ++nt) {
        bf16x8 wf = *(const bf16x8*)&Bs[((nt << 4) + m16) * LDT + (kh << 5) + koff];
        acc[0][nt] = __builtin_amdgcn_mfma_f32_16x16x32_bf16(af0, wf, acc[0][nt], 0, 0, 0);
        acc[1][nt] = __builtin_amdgcn_mfma_f32_16x16x32_bf16(af1, wf, acc[1][nt], 0, 0, 0);
      }
    }
    __builtin_amdgcn_s_setprio(0);
  }

  const int b = i0 >> 11, l0 = i0 & 2047, h = n0 >> 6;
#pragma unroll
  for (int nt = 0; nt < 4; ++nt) {
    float bn = bias[n0 + (nt << 4) + m16];
    int d = (nt << 4) + m16;
#pragma unroll
    for (int mi = 0; mi < 2; ++mi) {
#pragma unroll
      for (int r = 0; r < 4; ++r) {
        int il = (wave << 5) + (mi << 4) + (quad << 2) + r;
        ushort qb = f2bf((acc[mi][nt][r] + bn) * oscale);
        out[((size_t)(b * 8 + h) * 2048 + l0 + il) * 64 + d] = qb;
        if (QREL) As[il * LDT + d] = qb;  // wave-local rows; no barrier needed
      }
    }
  }

  if (QREL) {
    __asm__ volatile("s_waitcnt lgkmcnt(0)" ::: "memory");
    // A-frags: this wave's 32 rows (two 16-row groups), loaded once.
    bf16x8 afq[2][2];
#pragma unroll
    for (int g = 0; g < 2; ++g)
#pragma unroll
      for (int kh = 0; kh < 2; ++kh)
        afq[g][kh] = *(const bf16x8*)&As[((wave << 5) + (g << 4) + m16) * LDT +
                                         (kh << 5) + koff];
    const int bh = b * 8 + h;
    for (int rc = 0; rc < 32; ++rc) {
      const ushort* rp = rel8 + (size_t)((rc << 4) + m16) * 64;
      bf16x8 wf0 = *(const bf16x8*)(rp + koff);
      bf16x8 wf1 = *(const bf16x8*)(rp + 32 + koff);
      int r = (rc << 4) + m16;
#pragma unroll
      for (int g = 0; g < 2; ++g) {
        f32x4 aq = {0.f, 0.f, 0.f, 0.f};
        aq = __builtin_amdgcn_mfma_f32_16x16x32_bf16(afq[g][0], wf0, aq, 0, 0, 0);
        aq = __builtin_amdgcn_mfma_f32_16x16x32_bf16(afq[g][1], wf1, aq, 0, 0, 0);
        if (r < NREL_PAD) {
#pragma unroll
          for (int rg = 0; rg < 4; ++rg) {
            // within-batch l index (NOT global i0): l0 + local row
            int l = l0 + (wave << 5) + (g << 4) + (quad << 2) + rg;
            qrelh[((size_t)bh * 2048 + l) * NREL_PAD + r] = f2h(aq[rg]);
          }
        }
      }
    }
  }
}

// Merged QKV projection + fused qrel. Grid (8, 32, 3). z=0: Q (pre-scaled
// 0.125) + qrel; z=1: K; z=2: V via two sequential MODE-1 tiles.
__global__ __launch_bounds__(256) void gemm_qkv(
    const float* __restrict__ q, const float* __restrict__ k,
    const float* __restrict__ v, const ushort* __restrict__ Wt,
    const float* __restrict__ bq, const float* __restrict__ bk,
    const float* __restrict__ bv, const int* __restrict__ mask,
    const ushort* __restrict__ rel8, ushort* __restrict__ Qw,
    ushort* __restrict__ Kw, ushort* __restrict__ Vtw,
    ushort* __restrict__ qrelh) {
  const int z = blockIdx.z;
  if (z == 0) {
    gemm_qk128<1>(q, Wt, bq, Qw, rel8, qrelh, blockIdx.x, blockIdx.y, 0.125f);
  } else if (z == 1) {
    gemm_qk128<0>(k, Wt + 262144, bk, Kw, nullptr, nullptr, blockIdx.x,
                  blockIdx.y, 1.f);
  } else {
#pragma unroll
    for (int s = 0; s < 2; ++s)
      gemm_tile_body<1, 1>(v, Wt + 2 * 262144, bv, mask, (void*)Vtw,
                           blockIdx.x, blockIdx.y * 2 + s, 1.f);
  }
}

// ============================================================================
// qrel gather (fp16 table) for one 64-j tile; wave-uniform clamp shortcut
// with hoisted edge values (zero loads on fully-clamped tiles).
// ============================================================================
__device__ __forceinline__ void gather_qv(float qv[4][4],
                                          const ushort* __restrict__ qrow,
                                          float e_lo, float e_hi,
                                          int iq, int iw0, int j0, int quad) {
  if (j0 - iw0 >= 264) {
#pragma unroll
    for (int jt = 0; jt < 4; ++jt)
#pragma unroll
      for (int r = 0; r < 4; ++r) qv[jt][r] = e_hi;
  } else if (iw0 - j0 >= 312) {
#pragma unroll
    for (int jt = 0; jt < 4; ++jt)
#pragma unroll
      for (int r = 0; r < 4; ++r) qv[jt][r] = e_lo;
  } else {
#pragma unroll
    for (int jt = 0; jt < 4; ++jt) {
#pragma unroll
      for (int r = 0; r < 4; ++r) {
        int j = j0 + (jt << 4) + (quad << 2) + r;
        int rr = min(NREL - 1, max(0, j - iq + 249));
        qv[jt][r] = h2f(qrow[rr]);
      }
    }
  }
}

// ============================================================================
// Flash attention (R6/R9 structure, frozen): LDS-staged K/V, register
// prefetch, swapped-operand QK^T with bias-initialized C, in-register
// softmax, defer-max, MFMA l-accumulation, XCD swizzle, 2x unroll.
// ============================================================================
__global__ __launch_bounds__(256) void flash_attn(
    const ushort* __restrict__ Qw, const ushort* __restrict__ Kw,
    const ushort* __restrict__ Vt, const ushort* __restrict__ qrelh,
    const ushort* __restrict__ maskbf, ushort* __restrict__ attnbf) {
  __shared__ ushort QPs[64 * LDB];  // Q tile [i][d]; later P [i][j]
  __shared__ ushort Ks[64 * LDB];   // [j][d]
  __shared__ ushort Vs[64 * LDB];   // [d][j]
  const int t = threadIdx.x;
  const int lane = t & 63, wave = t >> 6;
  const int m16 = lane & 15, quad = lane >> 4;
  const int koff = quad << 3;
  const int bid = ((int)blockIdx.y << 5) + (int)blockIdx.x;
  const int swz = ((bid & 7) << 6) + (bid >> 3);  // XCD-contiguous chunks
  const int i0 = (swz & 31) << 6;
  const int bh = swz >> 5;
  const int b = bh >> 3, h = bh & 7;
  const ushort* Qb = Qw + (size_t)bh * 2048 * 64;
  const ushort* Kb = Kw + (size_t)bh * 2048 * 64;
  const ushort* Vb = Vt + (size_t)bh * 64 * 2048;
  const ushort* mbf = maskbf + b * 2048;
  const int iw0 = i0 + (wave << 4);
  const int iq = iw0 + m16;  // this lane's output row
  const ushort* qrow = qrelh + ((size_t)bh * 2048 + iq) * NREL_PAD;
  const float e_lo = h2f(qrow[0]), e_hi = h2f(qrow[NREL - 1]);

  const int row0 = t >> 3, off0 = (t & 7) << 3;
  const int row1 = (t + 256) >> 3, off1 = ((t + 256) & 7) << 3;

  // Q tile -> LDS
  *(uint4*)&QPs[row0 * LDB + off0] =
      *(const uint4*)(Qb + (size_t)(i0 + row0) * 64 + off0);
  *(uint4*)&QPs[row1 * LDB + off1] =
      *(const uint4*)(Qb + (size_t)(i0 + row1) * 64 + off1);
  __syncthreads();

  bf16x8 qa0 = *(const bf16x8*)&QPs[((wave << 4) + m16) * LDB + koff];
  bf16x8 qa1 = *(const bf16x8*)&QPs[((wave << 4) + m16) * LDB + 32 + koff];

  float m_i = -INFINITY;
  f32x4 oacc[4];
  f32x4 lacc = {0.f, 0.f, 0.f, 0.f};
#pragma unroll
  for (int dt = 0; dt < 4; ++dt) oacc[dt] = (f32x4){0.f, 0.f, 0.f, 0.f};

  // ---- prologue prefetch (set A) for j0 = 0 ----
  uint4 krA0 = *(const uint4*)(Kb + (size_t)row0 * 64 + off0);
  uint4 krA1 = *(const uint4*)(Kb + (size_t)row1 * 64 + off1);
  uint4 vrA0 = *(const uint4*)(Vb + (size_t)row0 * 2048 + off0);
  uint4 vrA1 = *(const uint4*)(Vb + (size_t)row1 * 2048 + off1);
  bf16x8 mfA0 = *(const bf16x8*)(mbf + koff);
  bf16x8 mfA1 = *(const bf16x8*)(mbf + 32 + koff);
  float qvA[4][4];
  gather_qv(qvA, qrow, e_lo, e_hi, iq, iw0, 0, quad);
  uint4 krB0, krB1, vrB0, vrB1;
  bf16x8 mfB0, mfB1;
  float qvB[4][4];

#define FLASH_STEP(KR0, KR1, VR0, VR1, MF0, MF1, QV,                          \
                   KN0, KN1, VN0, VN1, MG0, MG1, QN, JN)                      \
  do {                                                                        \
    __syncthreads();                                                          \
    *(uint4*)&Ks[row0 * LDB + off0] = KR0;                                    \
    *(uint4*)&Ks[row1 * LDB + off1] = KR1;                                    \
    *(uint4*)&Vs[row0 * LDB + off0] = VR0;                                    \
    *(uint4*)&Vs[row1 * LDB + off1] = VR1;                                    \
    __syncthreads();                                                          \
    KN0 = *(const uint4*)(Kb + (size_t)((JN) + row0) * 64 + off0);            \
    KN1 = *(const uint4*)(Kb + (size_t)((JN) + row1) * 64 + off1);            \
    VN0 = *(const uint4*)(Vb + (size_t)row0 * 2048 + (JN) + off0);            \
    VN1 = *(const uint4*)(Vb + (size_t)row1 * 2048 + (JN) + off1);            \
    MG0 = *(const bf16x8*)(mbf + (JN) + koff);                                \
    MG1 = *(const bf16x8*)(mbf + (JN) + 32 + koff);                           \
    gather_qv(QN, qrow, e_lo, e_hi, iq, iw0, (JN), quad);                     \
    f32x4 sacc[4];                                                            \
    __builtin_amdgcn_s_setprio(1);                                            \
    _Pragma("unroll")                                                         \
    for (int jt = 0; jt < 4; ++jt) {                                          \
      bf16x8 kf0 = *(const bf16x8*)&Ks[((jt << 4) + m16) * LDB + koff];       \
      bf16x8 kf1 = *(const bf16x8*)&Ks[((jt << 4) + m16) * LDB + 32 + koff];  \
      f32x4 z = {QV[jt][0], QV[jt][1], QV[jt][2], QV[jt][3]};                 \
      z = __builtin_amdgcn_mfma_f32_16x16x32_bf16(kf0, qa0, z, 0, 0, 0);      \
      z = __builtin_amdgcn_mfma_f32_16x16x32_bf16(kf1, qa1, z, 0, 0, 0);      \
      sacc[jt] = z;                                                           \
    }                                                                         \
    __builtin_amdgcn_s_setprio(0);                                            \
    float t0 = fmaxf(fmaxf(sacc[0][0], sacc[0][1]),                           \
                     fmaxf(sacc[0][2], sacc[0][3]));                          \
    float t1 = fmaxf(fmaxf(sacc[1][0], sacc[1][1]),                           \
                     fmaxf(sacc[1][2], sacc[1][3]));                          \
    float t2 = fmaxf(fmaxf(sacc[2][0], sacc[2][1]),                           \
                     fmaxf(sacc[2][2], sacc[2][3]));                          \
    float t3 = fmaxf(fmaxf(sacc[3][0], sacc[3][1]),                           \
                     fmaxf(sacc[3][2], sacc[3][3]));                          \
    float mx = fmaxf(fmaxf(t0, t1), fmaxf(t2, t3));                           \
    mx = fmaxf(mx, __shfl_xor(mx, 16));                                       \
    mx = fmaxf(mx, __shfl_xor(mx, 32));                                       \
    if (__any(mx > m_i + 8.f)) {                                              \
      float mnew = fmaxf(m_i, mx);                                            \
      float al = __expf(m_i - mnew);                                          \
      m_i = mnew;                                                             \
      _Pragma("unroll")                                                       \
      for (int dt = 0; dt < 4; ++dt) {                                        \
        oacc[dt][0] *= al; oacc[dt][1] *= al;                                 \
        oacc[dt][2] *= al; oacc[dt][3] *= al;                                 \
      }                                                                       \
      lacc[0] *= al; lacc[1] *= al; lacc[2] *= al; lacc[3] *= al;             \
    }                                                                         \
    const int prow = ((wave << 4) + m16) * LDB;                               \
    _Pragma("unroll")                                                         \
    for (int jt = 0; jt < 4; ++jt) {                                          \
      ushort4 pk;                                                             \
      pk.x = f2bf(__expf(sacc[jt][0] - m_i));                                 \
      pk.y = f2bf(__expf(sacc[jt][1] - m_i));                                 \
      pk.z = f2bf(__expf(sacc[jt][2] - m_i));                                 \
      pk.w = f2bf(__expf(sacc[jt][3] - m_i));                                 \
      *(ushort4*)&QPs[prow + (jt << 4) + (quad << 2)] = pk;                   \
    }                                                                         \
    __asm__ volatile("s_waitcnt lgkmcnt(0)" ::: "memory");                    \
    bf16x8 pa0 = *(const bf16x8*)&QPs[prow + koff];                           \
    bf16x8 pa1 = *(const bf16x8*)&QPs[prow + 32 + koff];                      \
    __builtin_amdgcn_s_setprio(1);                                            \
    lacc = __builtin_amdgcn_mfma_f32_16x16x32_bf16(MF0, pa0, lacc, 0, 0, 0);  \
    lacc = __builtin_amdgcn_mfma_f32_16x16x32_bf16(MF1, pa1, lacc, 0, 0, 0);  \
    _Pragma("unroll")                                                         \
    for (int dt = 0; dt < 4; ++dt) {                                          \
      bf16x8 vf0 = *(const bf16x8*)&Vs[((dt << 4) + m16) * LDB + koff];       \
      bf16x8 vf1 = *(const bf16x8*)&Vs[((dt << 4) + m16) * LDB + 32 + koff];  \
      oacc[dt] =                                                              \
          __builtin_amdgcn_mfma_f32_16x16x32_bf16(vf0, pa0, oacc[dt], 0, 0, 0); \
      oacc[dt] =                                                              \
          __builtin_amdgcn_mfma_f32_16x16x32_bf16(vf1, pa1, oacc[dt], 0, 0, 0); \
    }                                                                         \
    __builtin_amdgcn_s_setprio(0);                                            \
  } while (0)

  for (int j0 = 0; j0 < 2048; j0 += 128) {
    FLASH_STEP(krA0, krA1, vrA0, vrA1, mfA0, mfA1, qvA,
               krB0, krB1, vrB0, vrB1, mfB0, mfB1, qvB, j0 + 64);
    FLASH_STEP(krB0, krB1, vrB0, vrB1, mfB0, mfB1, qvB,
               krA0, krA1, vrA0, vrA1, mfA0, mfA1, qvA, (j0 + 128) & 2047);
  }
#undef FLASH_STEP

  // epilogue: lane holds O[iq][d = dt*16 + quad*4 + r]; l = lacc[0]
  float inv = 1.0f / lacc[0];
  ushort* dst = attnbf + (size_t)(b * 2048 + iq) * 512 + h * 64;
#pragma unroll
  for (int dt = 0; dt < 4; ++dt) {
    ushort4 st;
    st.x = f2bf(oacc[dt][0] * inv);
    st.y = f2bf(oacc[dt][1] * inv);
    st.z = f2bf(oacc[dt][2] * inv);
    st.w = f2bf(oacc[dt][3] * inv);
    *(ushort4*)(dst + (dt << 4) + (quad << 2)) = st;
  }
}

// ============================================================================
extern "C" void kernel_launch(void* const* d_in, const int* in_sizes, int n_in,
                              void* d_out, int out_size, void* d_ws,
                              size_t ws_size, hipStream_t stream) {
  const float* query = (const float*)d_in[0];
  const float* key   = (const float*)d_in[1];
  const float* value = (const float*)d_in[2];
  const int*   mask  = (const int*)d_in[3];
  const float* Wq = (const float*)d_in[4];
  const float* bq = (const float*)d_in[5];
  const float* Wk = (const float*)d_in[6];
  const float* bk = (const float*)d_in[7];
  const float* Wv = (const float*)d_in[8];
  const float* bv = (const float*)d_in[9];
  const float* Wo = (const float*)d_in[10];
  const float* bo = (const float*)d_in[11];
  const float* rel = (const float*)d_in[12];

  char* w = (char*)d_ws;
  size_t off = 0;
  ushort* Qw  = (ushort*)(w + off); off += (size_t)16 * 2048 * 64 * 2;       // 4 MB
  ushort* Kw  = (ushort*)(w + off); off += (size_t)16 * 2048 * 64 * 2;       // 4 MB
  ushort* Vtw = (ushort*)(w + off); off += (size_t)16 * 64 * 2048 * 2;       // 4 MB
  ushort* Wt  = (ushort*)(w + off); off += (size_t)4 * 512 * 512 * 2;        // 2 MB
  ushort* qrelh = (ushort*)(w + off); off += (size_t)16 * 2048 * NREL_PAD * 2; // 33 MB
  ushort* attnbf = (ushort*)(w + off); off += (size_t)4096 * 512 * 2;        // 4 MB
  ushort* maskbf = (ushort*)(w + off); off += (size_t)2 * 2048 * 2;          // 8 KB
  ushort* rel8 = (ushort*)(w + off); off += (size_t)512 * 64 * 2;            // 64 KB
  float* out = (float*)d_out;

  dim3 bb(256);
  hipLaunchKernelGGL(prep_wt, dim3(8, 8, 4), bb, 0, stream, Wq, Wk, Wv, Wo,
                     mask, rel, Wt, maskbf, rel8);
  hipLaunchKernelGGL(gemm_qkv, dim3(8, 32, 3), bb, 0, stream, query, key, value,
                     Wt, bq, bk, bv, mask, rel8, Qw, Kw, Vtw, qrelh);
  hipLaunchKernelGGL(flash_attn, dim3(32, 16), bb, 0, stream, Qw, Kw, Vtw,
                     qrelh, maskbf, attnbf);
  hipLaunchKernelGGL((gemm_tile<0, 0>), dim3(8, 64), bb, 0, stream, attnbf,
                     Wt + 3 * 262144, bo, (void*)out);
}

// Round 15
// 204.787 us; speedup vs baseline: 1.0442x; 1.0035x over previous
//
#include <hip/hip_runtime.h>
#include <math.h>

// Problem constants
#define NREL 499        // 2*MAX_LEN-1
#define NREL_PAD 504    // fp16 row stride (1008 B, 16-B aligned)
#define LDB 72          // bf16 LDS row stride (flash kernel)
#define LDT 72          // bf16 LDS row stride (gemm tiles)
#define KVSZ (64 * LDB) // one K or V buffer, in ushorts

typedef __attribute__((ext_vector_type(8))) short bf16x8;
typedef __attribute__((ext_vector_type(4))) float f32x4;

__device__ __forceinline__ float bf2f(ushort x) {
  union { unsigned u; float f; } v; v.u = ((unsigned)x) << 16; return v.f;
}
__device__ __forceinline__ ushort f2bf(float x) {
  union { float f; unsigned u; } v; v.f = x;
  return (ushort)((v.u + 0x8000u) >> 16);
}
__device__ __forceinline__ ushort f2h(float x) {
  union { _Float16 h; ushort u; } v; v.h = (_Float16)x; return v.u;
}
__device__ __forceinline__ float h2f(ushort u) {
  union { _Float16 h; ushort u; } v; v.u = u; return (float)v.h;
}
__device__ __forceinline__ bf16x8 pack8(float4 a, float4 b) {
  bf16x8 r;
  r[0] = (short)f2bf(a.x); r[1] = (short)f2bf(a.y);
  r[2] = (short)f2bf(a.z); r[3] = (short)f2bf(a.w);
  r[4] = (short)f2bf(b.x); r[5] = (short)f2bf(b.y);
  r[6] = (short)f2bf(b.z); r[7] = (short)f2bf(b.w);
  return r;
}

// ============================================================================
// prep_wt: Wt[z][n][k] (bf16) = W_z[k][n], z = {q,k,v,o}. Grid (8,8,4).
// Blocks (0,0,z): build maskbf[b][j] = mask ? 1.0bf : 0.0bf.
// Blocks (1,0,z): build rel8[512][64] bf16 = 8 * rel (rows >= 499 zeroed).
// ============================================================================
__global__ __launch_bounds__(256) void prep_wt(const float* __restrict__ W0,
                                               const float* __restrict__ W1,
                                               const float* __restrict__ W2,
                                               const float* __restrict__ W3,
                                               const int* __restrict__ mask,
                                               const float* __restrict__ rel,
                                               ushort* __restrict__ Wt,
                                               ushort* __restrict__ maskbf,
                                               ushort* __restrict__ rel8) {
  __shared__ float T[64][68];
  const int t = threadIdx.x;
  const int k0 = blockIdx.x * 64, n0 = blockIdx.y * 64, z = blockIdx.z;
  const float* W = (z == 0) ? W0 : (z == 1) ? W1 : (z == 2) ? W2 : W3;
#pragma unroll
  for (int s = 0; s < 4; ++s) {
    int idx = t + s * 256;
    int r = idx >> 4, c4 = (idx & 15) << 2;
    *(float4*)&T[r][c4] = *(const float4*)(W + (size_t)(k0 + r) * 512 + n0 + c4);
  }
  if (blockIdx.x == 0 && blockIdx.y == 0) {
    int base = z * 1024 + t * 4;
    int4 mv = *(const int4*)(mask + base);
    ushort4 mo;
    mo.x = mv.x ? 0x3F80 : 0; mo.y = mv.y ? 0x3F80 : 0;
    mo.z = mv.z ? 0x3F80 : 0; mo.w = mv.w ? 0x3F80 : 0;
    *(ushort4*)(maskbf + base) = mo;
  } else if (blockIdx.x == 1 && blockIdx.y == 0) {
    int base = z * 8192 + t * 32;
#pragma unroll
    for (int c = 0; c < 4; ++c) {
      int e0 = base + c * 8;
      ushort tmp[8];
#pragma unroll
      for (int k = 0; k < 8; ++k) {
        int e = e0 + k;
        float v = (e < NREL * 64) ? rel[e] * 8.f : 0.f;
        tmp[k] = f2bf(v);
      }
      *(ushort4*)(rel8 + e0) = make_ushort4(tmp[0], tmp[1], tmp[2], tmp[3]);
      *(ushort4*)(rel8 + e0 + 4) = make_ushort4(tmp[4], tmp[5], tmp[6], tmp[7]);
    }
  }
  __syncthreads();
#pragma unroll
  for (int s = 0; s < 4; ++s) {
    int idx = t + s * 256;
    int row = idx >> 4, c4 = (idx & 15) << 2;  // row = n_local, c4 = k_local
    ushort4 u = make_ushort4(f2bf(T[c4 + 0][row]), f2bf(T[c4 + 1][row]),
                             f2bf(T[c4 + 2][row]), f2bf(T[c4 + 3][row]));
    *(ushort4*)(Wt + (size_t)z * 262144 + (size_t)(n0 + row) * 512 + k0 + c4) = u;
  }
}

// ============================================================================
// gemm_tile_body (64x64): C = A @ Wt^T + bias. Proven R4 structure.
// AFP32=1: A fp32 cast to bf16 during staging.
// MODE 0: fp32 row-major out; MODE 1: bf16 Vt [bh][d][l] masked-zeroed.
// ============================================================================
template <int MODE, int AFP32>
__device__ __forceinline__ void gemm_tile_body(const void* __restrict__ Av,
                                               const ushort* __restrict__ Wt,
                                               const float* __restrict__ bias,
                                               const int* __restrict__ mvec,
                                               void* __restrict__ outv,
                                               int bx, int by, float oscale) {
  __shared__ ushort As[64 * LDT];
  __shared__ ushort Bs[64 * LDT];
  const int t = threadIdx.x;
  const int lane = t & 63, wave = t >> 6;
  const int m16 = lane & 15, quad = lane >> 4;
  const int koff = quad << 3;
  const int i0 = by * 64, n0 = bx * 64;
  const int row0 = t >> 3, off0 = (t & 7) << 3;
  const int row1 = (t + 256) >> 3, off1 = ((t + 256) & 7) << 3;
  const ushort* Ab16 = (const ushort*)Av + (size_t)i0 * 512;
  const float*  Ab32 = (const float*)Av + (size_t)i0 * 512;
  const ushort* Bb = Wt + (size_t)n0 * 512;

  uint4 ar0, ar1;
  float4 af00, af01, af10, af11;
  if (AFP32) {
    af00 = *(const float4*)(Ab32 + (size_t)row0 * 512 + off0);
    af01 = *(const float4*)(Ab32 + (size_t)row0 * 512 + off0 + 4);
    af10 = *(const float4*)(Ab32 + (size_t)row1 * 512 + off1);
    af11 = *(const float4*)(Ab32 + (size_t)row1 * 512 + off1 + 4);
  } else {
    ar0 = *(const uint4*)(Ab16 + (size_t)row0 * 512 + off0);
    ar1 = *(const uint4*)(Ab16 + (size_t)row1 * 512 + off1);
  }
  uint4 br0 = *(const uint4*)(Bb + (size_t)row0 * 512 + off0);
  uint4 br1 = *(const uint4*)(Bb + (size_t)row1 * 512 + off1);

  f32x4 acc[4] = {{0.f, 0.f, 0.f, 0.f}, {0.f, 0.f, 0.f, 0.f},
                  {0.f, 0.f, 0.f, 0.f}, {0.f, 0.f, 0.f, 0.f}};

  for (int ks = 0; ks < 8; ++ks) {
    __syncthreads();
    if (AFP32) {
      *(bf16x8*)&As[row0 * LDT + off0] = pack8(af00, af01);
      *(bf16x8*)&As[row1 * LDT + off1] = pack8(af10, af11);
    } else {
      *(uint4*)&As[row0 * LDT + off0] = ar0;
      *(uint4*)&As[row1 * LDT + off1] = ar1;
    }
    *(uint4*)&Bs[row0 * LDT + off0] = br0;
    *(uint4*)&Bs[row1 * LDT + off1] = br1;
    __syncthreads();

    const int kn = ((ks + 1) & 7) << 6;
    if (AFP32) {
      af00 = *(const float4*)(Ab32 + (size_t)row0 * 512 + kn + off0);
      af01 = *(const float4*)(Ab32 + (size_t)row0 * 512 + kn + off0 + 4);
      af10 = *(const float4*)(Ab32 + (size_t)row1 * 512 + kn + off1);
      af11 = *(const float4*)(Ab32 + (size_t)row1 * 512 + kn + off1 + 4);
    } else {
      ar0 = *(const uint4*)(Ab16 + (size_t)row0 * 512 + kn + off0);
      ar1 = *(const uint4*)(Ab16 + (size_t)row1 * 512 + kn + off1);
    }
    br0 = *(const uint4*)(Bb + (size_t)row0 * 512 + kn + off0);
    br1 = *(const uint4*)(Bb + (size_t)row1 * 512 + kn + off1);

    __builtin_amdgcn_s_setprio(1);
    if (MODE != 1) {
#pragma unroll
      for (int kh = 0; kh < 2; ++kh) {
        bf16x8 af = *(const bf16x8*)&As[((wave << 4) + m16) * LDT + (kh << 5) + koff];
#pragma unroll
        for (int nt = 0; nt < 4; ++nt) {
          bf16x8 wf = *(const bf16x8*)&Bs[((nt << 4) + m16) * LDT + (kh << 5) + koff];
          acc[nt] = __builtin_amdgcn_mfma_f32_16x16x32_bf16(af, wf, acc[nt], 0, 0, 0);
        }
      }
    } else {
#pragma unroll
      for (int kh = 0; kh < 2; ++kh) {
        bf16x8 wf = *(const bf16x8*)&Bs[((wave << 4) + m16) * LDT + (kh << 5) + koff];
#pragma unroll
        for (int it = 0; it < 4; ++it) {
          bf16x8 af = *(const bf16x8*)&As[((it << 4) + m16) * LDT + (kh << 5) + koff];
          acc[it] = __builtin_amdgcn_mfma_f32_16x16x32_bf16(wf, af, acc[it], 0, 0, 0);
        }
      }
    }
    __builtin_amdgcn_s_setprio(0);
  }

  if (MODE == 0) {
    float* out = (float*)outv;
#pragma unroll
    for (int nt = 0; nt < 4; ++nt) {
      float bn = bias[n0 + (nt << 4) + m16];
#pragma unroll
      for (int r = 0; r < 4; ++r) {
        int i = i0 + (wave << 4) + (quad << 2) + r;
        out[(size_t)i * 512 + n0 + (nt << 4) + m16] = acc[nt][r] + bn;
      }
    }
  } else {  // MODE 1: Vt [bh][d][l], masked columns -> 0
    ushort* out = (ushort*)outv;
    const int b = i0 >> 11, l0 = i0 & 2047, h = n0 >> 6;
    float4 b4 = *(const float4*)(bias + n0 + (wave << 4) + (quad << 2));
    float bb[4] = {b4.x, b4.y, b4.z, b4.w};
    float mkf[4];
#pragma unroll
    for (int it = 0; it < 4; ++it)
      mkf[it] = (mvec[b * 2048 + l0 + (it << 4) + m16] != 0) ? 1.f : 0.f;
#pragma unroll
    for (int r = 0; r < 4; ++r) {
      int d = (wave << 4) + (quad << 2) + r;
#pragma unroll
      for (int it = 0; it < 4; ++it) {
        out[((size_t)(b * 8 + h) * 64 + d) * 2048 + l0 + (it << 4) + m16] =
            f2bf((acc[it][r] + bb[r]) * mkf[it]);
      }
    }
  }
}

template <int MODE, int AFP32>
__global__ __launch_bounds__(256) void gemm_tile(const void* __restrict__ A,
                                                 const ushort* __restrict__ Wt,
                                                 const float* __restrict__ bias,
                                                 void* __restrict__ outv) {
  gemm_tile_body<MODE, AFP32>(A, Wt, bias, nullptr, outv, blockIdx.x,
                              blockIdx.y, 1.f);
}

// ============================================================================
// gemm_qk128: BM=128 x BN=64 tile, BK=64, fused fp32->bf16 A staging, MODE-2
// output (bf16 head-split [bh][l][d], scaled). QREL=1 additionally computes
// qrelh[bh][l][r] = Qrow . rel8[r] for the block's 128 rows x all 512 r,
// reusing the in-register Q tile (repacked via As; wave-local rows so no
// barrier, only lgkmcnt). Bit-identical to the old separate qrel_tile.
// ============================================================================
template <int QREL>
__device__ __forceinline__ void gemm_qk128(const float* __restrict__ A,
                                           const ushort* __restrict__ Wt,
                                           const float* __restrict__ bias,
                                           ushort* __restrict__ out,
                                           const ushort* __restrict__ rel8,
                                           ushort* __restrict__ qrelh,
                                           int bx, int by, float oscale) {
  __shared__ ushort As[128 * LDT];
  __shared__ ushort Bs[64 * LDT];
  const int t = threadIdx.x;
  const int lane = t & 63, wave = t >> 6;
  const int m16 = lane & 15, quad = lane >> 4;
  const int koff = quad << 3;
  const int i0 = by * 128, n0 = bx * 64;
  const float* Ab = A + (size_t)i0 * 512;
  const ushort* Bb = Wt + (size_t)n0 * 512;

  int arow[4], acol[4];
#pragma unroll
  for (int s = 0; s < 4; ++s) {
    int idx = t + s * 256;
    arow[s] = idx >> 3;
    acol[s] = (idx & 7) << 3;
  }
  const int brow0 = t >> 3, bcol0 = (t & 7) << 3;
  const int brow1 = (t + 256) >> 3, bcol1 = ((t + 256) & 7) << 3;

  float4 afA[4], afB[4];
  uint4 br0, br1;
#pragma unroll
  for (int s = 0; s < 4; ++s) {
    afA[s] = *(const float4*)(Ab + (size_t)arow[s] * 512 + acol[s]);
    afB[s] = *(const float4*)(Ab + (size_t)arow[s] * 512 + acol[s] + 4);
  }
  br0 = *(const uint4*)(Bb + (size_t)brow0 * 512 + bcol0);
  br1 = *(const uint4*)(Bb + (size_t)brow1 * 512 + bcol1);

  f32x4 acc[2][4];
#pragma unroll
  for (int mi = 0; mi < 2; ++mi)
#pragma unroll
    for (int nt = 0; nt < 4; ++nt) acc[mi][nt] = (f32x4){0.f, 0.f, 0.f, 0.f};

  for (int ks = 0; ks < 8; ++ks) {
    __syncthreads();
#pragma unroll
    for (int s = 0; s < 4; ++s)
      *(bf16x8*)&As[arow[s] * LDT + acol[s]] = pack8(afA[s], afB[s]);
    *(uint4*)&Bs[brow0 * LDT + bcol0] = br0;
    *(uint4*)&Bs[brow1 * LDT + bcol1] = br1;
    __syncthreads();

    const int kn = ((ks + 1) & 7) << 6;
#pragma unroll
    for (int s = 0; s < 4; ++s) {
      afA[s] = *(const float4*)(Ab + (size_t)arow[s] * 512 + kn + acol[s]);
      afB[s] = *(const float4*)(Ab + (size_t)arow[s] * 512 + kn + acol[s] + 4);
    }
    br0 = *(const uint4*)(Bb + (size_t)brow0 * 512 + kn + bcol0);
    br1 = *(const uint4*)(Bb + (size_t)brow1 * 512 + kn + bcol1);

    __builtin_amdgcn_s_setprio(1);
#pragma unroll
    for (int kh = 0; kh < 2; ++kh) {
      bf16x8 af0 = *(const bf16x8*)&As[((wave << 5) + m16) * LDT + (kh << 5) + koff];
      bf16x8 af1 = *(const bf16x8*)&As[((wave << 5) + 16 + m16) * LDT + (kh << 5) + koff];
#pragma unroll
      for (int nt = 0; nt < 4; ++nt) {
        bf16x8 wf = *(const bf16x8*)&Bs[((nt << 4) + m16) * LDT + (kh << 5) + koff];
        acc[0][nt] = __builtin_amdgcn_mfma_f32_16x16x32_bf16(af0, wf, acc[0][nt], 0, 0, 0);
        acc[1][nt] = __builtin_amdgcn_mfma_f32_16x16x32_bf16(af1, wf, acc[1][nt], 0, 0, 0);
      }
    }
    __builtin_amdgcn_s_setprio(0);
  }

  const int b = i0 >> 11, l0 = i0 & 2047, h = n0 >> 6;
#pragma unroll
  for (int nt = 0; nt < 4; ++nt) {
    float bn = bias[n0 + (nt << 4) + m16];
    int d = (nt << 4) + m16;
#pragma unroll
    for (int mi = 0; mi < 2; ++mi) {
#pragma unroll
      for (int r = 0; r < 4; ++r) {
        int il = (wave << 5) + (mi << 4) + (quad << 2) + r;
        ushort qb = f2bf((acc[mi][nt][r] + bn) * oscale);
        out[((size_t)(b * 8 + h) * 2048 + l0 + il) * 64 + d] = qb;
        if (QREL) As[il * LDT + d] = qb;  // wave-local rows; no barrier needed
      }
    }
  }

  if (QREL) {
    __asm__ volatile("s_waitcnt lgkmcnt(0)" ::: "memory");
    // A-frags: this wave's 32 rows (two 16-row groups), loaded once.
    bf16x8 afq[2][2];
#pragma unroll
    for (int g = 0; g < 2; ++g)
#pragma unroll
      for (int kh = 0; kh < 2; ++kh)
        afq[g][kh] = *(const bf16x8*)&As[((wave << 5) + (g << 4) + m16) * LDT +
                                         (kh << 5) + koff];
    const int bh = b * 8 + h;
    for (int rc = 0; rc < 32; ++rc) {
      const ushort* rp = rel8 + (size_t)((rc << 4) + m16) * 64;
      bf16x8 wf0 = *(const bf16x8*)(rp + koff);
      bf16x8 wf1 = *(const bf16x8*)(rp + 32 + koff);
      int r = (rc << 4) + m16;
#pragma unroll
      for (int g = 0; g < 2; ++g) {
        f32x4 aq = {0.f, 0.f, 0.f, 0.f};
        aq = __builtin_amdgcn_mfma_f32_16x16x32_bf16(afq[g][0], wf0, aq, 0, 0, 0);
        aq = __builtin_amdgcn_mfma_f32_16x16x32_bf16(afq[g][1], wf1, aq, 0, 0, 0);
        if (r < NREL_PAD) {
#pragma unroll
          for (int rg = 0; rg < 4; ++rg) {
            // within-batch l index (NOT global i0): l0 + local row
            int l = l0 + (wave << 5) + (g << 4) + (quad << 2) + rg;
            qrelh[((size_t)bh * 2048 + l) * NREL_PAD + r] = f2h(aq[rg]);
          }
        }
      }
    }
  }
}

// Merged QKV projection + fused qrel. Grid (8, 32, 3). z=0: Q (pre-scaled
// 0.125) + qrel; z=1: K; z=2: V via two sequential MODE-1 tiles.
__global__ __launch_bounds__(256) void gemm_qkv(
    const float* __restrict__ q, const float* __restrict__ k,
    const float* __restrict__ v, const ushort* __restrict__ Wt,
    const float* __restrict__ bq, const float* __restrict__ bk,
    const float* __restrict__ bv, const int* __restrict__ mask,
    const ushort* __restrict__ rel8, ushort* __restrict__ Qw,
    ushort* __restrict__ Kw, ushort* __restrict__ Vtw,
    ushort* __restrict__ qrelh) {
  const int z = blockIdx.z;
  if (z == 0) {
    gemm_qk128<1>(q, Wt, bq, Qw, rel8, qrelh, blockIdx.x, blockIdx.y, 0.125f);
  } else if (z == 1) {
    gemm_qk128<0>(k, Wt + 262144, bk, Kw, nullptr, nullptr, blockIdx.x,
                  blockIdx.y, 1.f);
  } else {
#pragma unroll
    for (int s = 0; s < 2; ++s)
      gemm_tile_body<1, 1>(v, Wt + 2 * 262144, bv, mask, (void*)Vtw,
                           blockIdx.x, blockIdx.y * 2 + s, 1.f);
  }
}

// ============================================================================
// qrel gather (fp16 table) for one 64-j tile; wave-uniform clamp shortcut
// with hoisted edge values (zero loads on fully-clamped tiles).
// ============================================================================
__device__ __forceinline__ void gather_qv(float qv[4][4],
                                          const ushort* __restrict__ qrow,
                                          float e_lo, float e_hi,
                                          int iq, int iw0, int j0, int quad) {
  if (j0 - iw0 >= 264) {
#pragma unroll
    for (int jt = 0; jt < 4; ++jt)
#pragma unroll
      for (int r = 0; r < 4; ++r) qv[jt][r] = e_hi;
  } else if (iw0 - j0 >= 312) {
#pragma unroll
    for (int jt = 0; jt < 4; ++jt)
#pragma unroll
      for (int r = 0; r < 4; ++r) qv[jt][r] = e_lo;
  } else {
#pragma unroll
    for (int jt = 0; jt < 4; ++jt) {
#pragma unroll
      for (int r = 0; r < 4; ++r) {
        int j = j0 + (jt << 4) + (quad << 2) + r;
        int rr = min(NREL - 1, max(0, j - iq + 249));
        qv[jt][r] = h2f(qrow[rr]);
      }
    }
  }
}

// ============================================================================
// Flash attention (R14 algorithm; LDS K/V DOUBLE-BUFFERED -> ONE barrier per
// 64-j tile instead of two). Iter t: write regs(tile t+1) into buf[nxt]
// (nobody reads nxt now — last reads were before prev barrier), load tile
// t+2 into regs, compute tile t from buf[cur], then a single barrier both
// publishes buf[nxt] and retires buf[cur] reads. Single kr/vr register set
// (kn/vn eliminated). Swapped QK^T, defer-max, MFMA-l, XCD swizzle frozen.
// ============================================================================
__global__ __launch_bounds__(256) void flash_attn(
    const ushort* __restrict__ Qw, const ushort* __restrict__ Kw,
    const ushort* __restrict__ Vt, const ushort* __restrict__ qrelh,
    const ushort* __restrict__ maskbf, ushort* __restrict__ attnbf) {
  __shared__ ushort QPs[64 * LDB];   // Q tile [i][d]; later P [i][j]
  __shared__ ushort Ks[2 * KVSZ];    // [j][d] double-buffered
  __shared__ ushort Vs[2 * KVSZ];    // [d][j] double-buffered
  const int t = threadIdx.x;
  const int lane = t & 63, wave = t >> 6;
  const int m16 = lane & 15, quad = lane >> 4;
  const int koff = quad << 3;
  const int bid = ((int)blockIdx.y << 5) + (int)blockIdx.x;
  const int swz = ((bid & 7) << 6) + (bid >> 3);  // XCD-contiguous chunks
  const int i0 = (swz & 31) << 6;
  const int bh = swz >> 5;
  const int b = bh >> 3, h = bh & 7;
  const ushort* Qb = Qw + (size_t)bh * 2048 * 64;
  const ushort* Kb = Kw + (size_t)bh * 2048 * 64;
  const ushort* Vb = Vt + (size_t)bh * 64 * 2048;
  const ushort* mbf = maskbf + b * 2048;
  const int iw0 = i0 + (wave << 4);
  const int iq = iw0 + m16;  // this lane's output row
  const ushort* qrow = qrelh + ((size_t)bh * 2048 + iq) * NREL_PAD;
  const float e_lo = h2f(qrow[0]), e_hi = h2f(qrow[NREL - 1]);

  const int row0 = t >> 3, off0 = (t & 7) << 3;
  const int row1 = (t + 256) >> 3, off1 = ((t + 256) & 7) << 3;

  // Q tile -> LDS
  *(uint4*)&QPs[row0 * LDB + off0] =
      *(const uint4*)(Qb + (size_t)(i0 + row0) * 64 + off0);
  *(uint4*)&QPs[row1 * LDB + off1] =
      *(const uint4*)(Qb + (size_t)(i0 + row1) * 64 + off1);

  // K/V tile 0 -> regs
  uint4 kr0 = *(const uint4*)(Kb + (size_t)row0 * 64 + off0);
  uint4 kr1 = *(const uint4*)(Kb + (size_t)row1 * 64 + off1);
  uint4 vr0 = *(const uint4*)(Vb + (size_t)row0 * 2048 + off0);
  uint4 vr1 = *(const uint4*)(Vb + (size_t)row1 * 2048 + off1);
  __syncthreads();  // Q visible

  bf16x8 qa0 = *(const bf16x8*)&QPs[((wave << 4) + m16) * LDB + koff];
  bf16x8 qa1 = *(const bf16x8*)&QPs[((wave << 4) + m16) * LDB + 32 + koff];

  // stage tile 0 into buf0; load tile 1 into regs
  *(uint4*)&Ks[row0 * LDB + off0] = kr0;
  *(uint4*)&Ks[row1 * LDB + off1] = kr1;
  *(uint4*)&Vs[row0 * LDB + off0] = vr0;
  *(uint4*)&Vs[row1 * LDB + off1] = vr1;
  kr0 = *(const uint4*)(Kb + (size_t)(64 + row0) * 64 + off0);
  kr1 = *(const uint4*)(Kb + (size_t)(64 + row1) * 64 + off1);
  vr0 = *(const uint4*)(Vb + (size_t)row0 * 2048 + 64 + off0);
  vr1 = *(const uint4*)(Vb + (size_t)row1 * 2048 + 64 + off1);

  bf16x8 mfA0 = *(const bf16x8*)(mbf + koff);
  bf16x8 mfA1 = *(const bf16x8*)(mbf + 32 + koff);
  float qvA[4][4];
  gather_qv(qvA, qrow, e_lo, e_hi, iq, iw0, 0, quad);
  bf16x8 mfB0, mfB1;
  float qvB[4][4];

  float m_i = -INFINITY;
  f32x4 oacc[4];
  f32x4 lacc = {0.f, 0.f, 0.f, 0.f};
#pragma unroll
  for (int dt = 0; dt < 4; ++dt) oacc[dt] = (f32x4){0.f, 0.f, 0.f, 0.f};

  __syncthreads();  // buf0 visible

// One 64-j tile. CUR/NXT are compile-time buffer byte bases (in ushorts).
// Consumes QV/MF (tile t), prefetches QN/MG (tile t+1, index JN1) and
// loads regs for tile t+2 (index JN2). Single barrier at the end.
#define FLASH_STEP(CUR, NXT, QV, MF0, MF1, QN, MG0, MG1, JN1, JN2)            \
  do {                                                                        \
    /* stage tile t+1 (in regs) into buf[NXT] — no reader of NXT now */       \
    *(uint4*)&Ks[(NXT) + row0 * LDB + off0] = kr0;                            \
    *(uint4*)&Ks[(NXT) + row1 * LDB + off1] = kr1;                            \
    *(uint4*)&Vs[(NXT) + row0 * LDB + off0] = vr0;                            \
    *(uint4*)&Vs[(NXT) + row1 * LDB + off1] = vr1;                            \
    /* load tile t+2 into regs (consumed next iter) */                        \
    kr0 = *(const uint4*)(Kb + (size_t)((JN2) + row0) * 64 + off0);           \
    kr1 = *(const uint4*)(Kb + (size_t)((JN2) + row1) * 64 + off1);           \
    vr0 = *(const uint4*)(Vb + (size_t)row0 * 2048 + (JN2) + off0);           \
    vr1 = *(const uint4*)(Vb + (size_t)row1 * 2048 + (JN2) + off1);           \
    /* prefetch mask/qrel for tile t+1 */                                     \
    MG0 = *(const bf16x8*)(mbf + (JN1) + koff);                               \
    MG1 = *(const bf16x8*)(mbf + (JN1) + 32 + koff);                          \
    gather_qv(QN, qrow, e_lo, e_hi, iq, iw0, (JN1), quad);                    \
    /* QK^T from buf[CUR], bias-initialized */                                \
    f32x4 sacc[4];                                                            \
    __builtin_amdgcn_s_setprio(1);                                            \
    _Pragma("unroll")                                                         \
    for (int jt = 0; jt < 4; ++jt) {                                          \
      bf16x8 kf0 = *(const bf16x8*)&Ks[(CUR) + ((jt << 4) + m16) * LDB + koff]; \
      bf16x8 kf1 =                                                            \
          *(const bf16x8*)&Ks[(CUR) + ((jt << 4) + m16) * LDB + 32 + koff];   \
      f32x4 z = {QV[jt][0], QV[jt][1], QV[jt][2], QV[jt][3]};                 \
      z = __builtin_amdgcn_mfma_f32_16x16x32_bf16(kf0, qa0, z, 0, 0, 0);      \
      z = __builtin_amdgcn_mfma_f32_16x16x32_bf16(kf1, qa1, z, 0, 0, 0);      \
      sacc[jt] = z;                                                           \
    }                                                                         \
    __builtin_amdgcn_s_setprio(0);                                            \
    float t0 = fmaxf(fmaxf(sacc[0][0], sacc[0][1]),                           \
                     fmaxf(sacc[0][2], sacc[0][3]));                          \
    float t1 = fmaxf(fmaxf(sacc[1][0], sacc[1][1]),                           \
                     fmaxf(sacc[1][2], sacc[1][3]));                          \
    float t2 = fmaxf(fmaxf(sacc[2][0], sacc[2][1]),                           \
                     fmaxf(sacc[2][2], sacc[2][3]));                          \
    float t3 = fmaxf(fmaxf(sacc[3][0], sacc[3][1]),                           \
                     fmaxf(sacc[3][2], sacc[3][3]));                          \
    float mx = fmaxf(fmaxf(t0, t1), fmaxf(t2, t3));                           \
    mx = fmaxf(mx, __shfl_xor(mx, 16));                                       \
    mx = fmaxf(mx, __shfl_xor(mx, 32));                                       \
    if (__any(mx > m_i + 8.f)) {                                              \
      float mnew = fmaxf(m_i, mx);                                            \
      float al = __expf(m_i - mnew);                                          \
      m_i = mnew;                                                             \
      _Pragma("unroll")                                                       \
      for (int dt = 0; dt < 4; ++dt) {                                        \
        oacc[dt][0] *= al; oacc[dt][1] *= al;                                 \
        oacc[dt][2] *= al; oacc[dt][3] *= al;                                 \
      }                                                                       \
      lacc[0] *= al; lacc[1] *= al; lacc[2] *= al; lacc[3] *= al;             \
    }                                                                         \
    const int prow = ((wave << 4) + m16) * LDB;                               \
    _Pragma("unroll")                                                         \
    for (int jt = 0; jt < 4; ++jt) {                                          \
      ushort4 pk;                                                             \
      pk.x = f2bf(__expf(sacc[jt][0] - m_i));                                 \
      pk.y = f2bf(__expf(sacc[jt][1] - m_i));                                 \
      pk.z = f2bf(__expf(sacc[jt][2] - m_i));                                 \
      pk.w = f2bf(__expf(sacc[jt][3] - m_i));                                 \
      *(ushort4*)&QPs[prow + (jt << 4) + (quad << 2)] = pk;                   \
    }                                                                         \
    __asm__ volatile("s_waitcnt lgkmcnt(0)" ::: "memory");                    \
    bf16x8 pa0 = *(const bf16x8*)&QPs[prow + koff];                           \
    bf16x8 pa1 = *(const bf16x8*)&QPs[prow + 32 + koff];                      \
    __builtin_amdgcn_s_setprio(1);                                            \
    lacc = __builtin_amdgcn_mfma_f32_16x16x32_bf16(MF0, pa0, lacc, 0, 0, 0);  \
    lacc = __builtin_amdgcn_mfma_f32_16x16x32_bf16(MF1, pa1, lacc, 0, 0, 0);  \
    _Pragma("unroll")                                                         \
    for (int dt = 0; dt < 4; ++dt) {                                          \
      bf16x8 vf0 =                                                            \
          *(const bf16x8*)&Vs[(CUR) + ((dt << 4) + m16) * LDB + koff];        \
      bf16x8 vf1 =                                                            \
          *(const bf16x8*)&Vs[(CUR) + ((dt << 4) + m16) * LDB + 32 + koff];   \
      oacc[dt] =                                                              \
          __builtin_amdgcn_mfma_f32_16x16x32_bf16(vf0, pa0, oacc[dt], 0, 0, 0); \
      oacc[dt] =                                                              \
          __builtin_amdgcn_mfma_f32_16x16x32_bf16(vf1, pa1, oacc[dt], 0, 0, 0); \
    }                                                                         \
    __builtin_amdgcn_s_setprio(0);                                            \
    __syncthreads(); /* publish buf[NXT]; retire buf[CUR] reads */            \
  } while (0)

  for (int j0 = 0; j0 < 2048; j0 += 128) {
    FLASH_STEP(0, KVSZ, qvA, mfA0, mfA1, qvB, mfB0, mfB1,
               j0 + 64, (j0 + 128) & 2047);
    FLASH_STEP(KVSZ, 0, qvB, mfB0, mfB1, qvA, mfA0, mfA1,
               (j0 + 128) & 2047, (j0 + 192) & 2047);
  }
#undef FLASH_STEP

  // epilogue: lane holds O[iq][d = dt*16 + quad*4 + r]; l = lacc[0]
  float inv = 1.0f / lacc[0];
  ushort* dst = attnbf + (size_t)(b * 2048 + iq) * 512 + h * 64;
#pragma unroll
  for (int dt = 0; dt < 4; ++dt) {
    ushort4 st;
    st.x = f2bf(oacc[dt][0] * inv);
    st.y = f2bf(oacc[dt][1] * inv);
    st.z = f2bf(oacc[dt][2] * inv);
    st.w = f2bf(oacc[dt][3] * inv);
    *(ushort4*)(dst + (dt << 4) + (quad << 2)) = st;
  }
}

// ============================================================================
extern "C" void kernel_launch(void* const* d_in, const int* in_sizes, int n_in,
                              void* d_out, int out_size, void* d_ws,
                              size_t ws_size, hipStream_t stream) {
  const float* query = (const float*)d_in[0];
  const float* key   = (const float*)d_in[1];
  const float* value = (const float*)d_in[2];
  const int*   mask  = (const int*)d_in[3];
  const float* Wq = (const float*)d_in[4];
  const float* bq = (const float*)d_in[5];
  const float* Wk = (const float*)d_in[6];
  const float* bk = (const float*)d_in[7];
  const float* Wv = (const float*)d_in[8];
  const float* bv = (const float*)d_in[9];
  const float* Wo = (const float*)d_in[10];
  const float* bo = (const float*)d_in[11];
  const float* rel = (const float*)d_in[12];

  char* w = (char*)d_ws;
  size_t off = 0;
  ushort* Qw  = (ushort*)(w + off); off += (size_t)16 * 2048 * 64 * 2;       // 4 MB
  ushort* Kw  = (ushort*)(w + off); off += (size_t)16 * 2048 * 64 * 2;       // 4 MB
  ushort* Vtw = (ushort*)(w + off); off += (size_t)16 * 64 * 2048 * 2;       // 4 MB
  ushort* Wt  = (ushort*)(w + off); off += (size_t)4 * 512 * 512 * 2;        // 2 MB
  ushort* qrelh = (ushort*)(w + off); off += (size_t)16 * 2048 * NREL_PAD * 2; // 33 MB
  ushort* attnbf = (ushort*)(w + off); off += (size_t)4096 * 512 * 2;        // 4 MB
  ushort* maskbf = (ushort*)(w + off); off += (size_t)2 * 2048 * 2;          // 8 KB
  ushort* rel8 = (ushort*)(w + off); off += (size_t)512 * 64 * 2;            // 64 KB
  float* out = (float*)d_out;

  dim3 bb(256);
  hipLaunchKernelGGL(prep_wt, dim3(8, 8, 4), bb, 0, stream, Wq, Wk, Wv, Wo,
                     mask, rel, Wt, maskbf, rel8);
  hipLaunchKernelGGL(gemm_qkv, dim3(8, 32, 3), bb, 0, stream, query, key, value,
                     Wt, bq, bk, bv, mask, rel8, Qw, Kw, Vtw, qrelh);
  hipLaunchKernelGGL(flash_attn, dim3(32, 16), bb, 0, stream, Qw, Kw, Vtw,
                     qrelh, maskbf, attnbf);
  hipLaunchKernelGGL((gemm_tile<0, 0>), dim3(8, 64), bb, 0, stream, attnbf,
                     Wt + 3 * 262144, bo, (void*)out);
}